// Round 1
// baseline (429.284 us; speedup 1.0000x reference)
//
#include <hip/hip_runtime.h>
#include <math.h>

#define Lh 2304
#define Ch 768
#define NHh 12
#define Bh 2
#define QS 4608   // row stride of fused qkv activation buffer (global q|k|v, local q|k|v)

typedef unsigned short ushort_t;
typedef unsigned int uint_t;
typedef __attribute__((ext_vector_type(8))) short bf16x8;
typedef __attribute__((ext_vector_type(4))) float f32x4;
#define MFMA16(a, b, c) __builtin_amdgcn_mfma_f32_16x16x32_bf16(a, b, c, 0, 0, 0)

// softmax in exp2 domain: exp(s*0.125 + m) == exp2(s*SCL2 + m*log2e)
#define SCL2 0.18033688f        // 0.125 * log2(e)
#define MSK2 1.4426950e9f       // 1e9  * log2(e)
#if __has_builtin(__builtin_amdgcn_exp2f)
#define EXP2F(x) __builtin_amdgcn_exp2f(x)
#else
#define EXP2F(x) exp2f(x)
#endif

__device__ __forceinline__ ushort_t f2bf(float f) {
    union { float f; uint_t u; } v; v.f = f;
    uint_t u = v.u + 0x7fffu + ((v.u >> 16) & 1u);   // RNE
    return (ushort_t)(u >> 16);
}
// pack 2 fp32 -> 2 bf16 (RNE) into one u32
__device__ __forceinline__ uint_t pack2bf(float a, float b) {
    return (uint_t)f2bf(a) | ((uint_t)f2bf(b) << 16);
}

// async global->LDS, 16B/lane, dest = wave-uniform base + lane*16
__device__ __forceinline__ void llds16(ushort_t* dst, const ushort_t* src) {
    __builtin_amdgcn_global_load_lds(
        (__attribute__((address_space(1))) void*)(const_cast<ushort_t*>(src)),
        (__attribute__((address_space(3))) void*)dst, 16, 0, 0);
}

// ---------------------------------------------------------------- layernorm (fp32 in, bf16 out)
__global__ __launch_bounds__(256)
void layernorm_bf16_kernel(const float* __restrict__ x, const float* __restrict__ w,
                           const float* __restrict__ b, ushort_t* __restrict__ y)
{
    int row = blockIdx.x;
    int tid = threadIdx.x;
    const float* xr = x + (size_t)row * Ch;
    float v0 = xr[tid], v1 = xr[tid + 256], v2 = xr[tid + 512];
    __shared__ float red[256];
    red[tid] = v0 + v1 + v2;
    __syncthreads();
    for (int st = 128; st > 0; st >>= 1) {
        if (tid < st) red[tid] += red[tid + st];
        __syncthreads();
    }
    float mean = red[0] * (1.0f / 768.0f);
    __syncthreads();
    float d0 = v0 - mean, d1 = v1 - mean, d2 = v2 - mean;
    red[tid] = d0 * d0 + d1 * d1 + d2 * d2;
    __syncthreads();
    for (int st = 128; st > 0; st >>= 1) {
        if (tid < st) red[tid] += red[tid + st];
        __syncthreads();
    }
    float rstd = rsqrtf(red[0] * (1.0f / 768.0f) + 1e-6f);
    ushort_t* yr = y + (size_t)row * Ch;
    yr[tid]       = f2bf(d0 * rstd * w[tid]       + b[tid]);
    yr[tid + 256] = f2bf(d1 * rstd * w[tid + 256] + b[tid + 256]);
    yr[tid + 512] = f2bf(d2 * rstd * w[tid + 512] + b[tid + 512]);
}

// ---------------------------------------------------------------- fused mask kernel
__global__ __launch_bounds__(64)
void mask_kernel(const float* __restrict__ mask, float* __restrict__ fg,
                 float* __restrict__ bgw)
{
    int win = blockIdx.x;            // 0..71
    int b = win / 36, w = win % 36;
    int wi = w / 6, wj = w % 6;
    int lane = threadIdx.x;          // 64
    int i = wi * 8 + (lane >> 3), j = wj * 8 + (lane & 7);
    const float* mb = mask + (size_t)b * 192 * 192 + (size_t)(i * 4) * 192 + j * 4;
    float s = 0.0f;
    #pragma unroll
    for (int di = 0; di < 4; ++di) {
        float4 v = *(const float4*)(mb + (size_t)di * 192);
        s += v.x + v.y + v.z + v.w;
    }
    float f = (s * (1.0f / 16.0f) > 0.4f) ? 1.0f : 0.0f;
    fg[b * Lh + i * 48 + j] = f;
    unsigned long long bg = __ballot(f == 0.0f);
    if (lane == 0) bgw[win] = bg ? 1.0f : 0.0f;
}

// ---------------------------------------------------------------- batched weight cast+transpose
__global__ __launch_bounds__(256)
void transpose_all_kernel(const float* __restrict__ w_qkv_g, const float* __restrict__ w_qkv_l,
                          const float* __restrict__ w_o_g, const float* __restrict__ w_o_l,
                          const float* __restrict__ w_fc1, const float* __restrict__ w_fc2,
                          ushort_t* __restrict__ wtq, ushort_t* __restrict__ wt_o_g,
                          ushort_t* __restrict__ wt_o_l, ushort_t* __restrict__ wt_fc1,
                          ushort_t* __restrict__ wt_fc2)
{
    int blk = blockIdx.x;
    const float* W; ushort_t* D; int K, N, nx, bx;
    const size_t CC = (size_t)Ch * Ch;
    if (blk < 432)       { int t = blk / 144; bx = blk % 144;
                           W = w_qkv_g + t * CC; D = wtq + t * CC; K = 768; N = 768; nx = 12; }
    else if (blk < 864)  { int r = blk - 432; int t = r / 144; bx = r % 144;
                           W = w_qkv_l + t * CC; D = wtq + (size_t)2304 * 768 + t * CC;
                           K = 768; N = 768; nx = 12; }
    else if (blk < 1008) { bx = blk - 864;  W = w_o_g; D = wt_o_g; K = 768; N = 768; nx = 12; }
    else if (blk < 1152) { bx = blk - 1008; W = w_o_l; D = wt_o_l; K = 768; N = 768; nx = 12; }
    else if (blk < 1728) { bx = blk - 1152; W = w_fc1; D = wt_fc1; K = 768; N = 3072; nx = 48; }
    else                 { bx = blk - 1728; W = w_fc2; D = wt_fc2; K = 3072; N = 768; nx = 12; }
    int n0 = (bx % nx) * 64;
    int k0 = (bx / nx) * 64;
    int tid = threadIdx.x;
    __shared__ float T[64][65];
    #pragma unroll
    for (int i = 0; i < 16; ++i) {
        int lin = i * 256 + tid;
        int r = lin >> 6, c = lin & 63;
        T[r][c] = W[(size_t)(k0 + r) * N + n0 + c];
    }
    __syncthreads();
    // vectorized: each unit = (n-row r, 4 consecutive k) -> one b64 store
    #pragma unroll
    for (int i = 0; i < 4; ++i) {
        int lin = i * 256 + tid;          // 0..1023
        int r = lin >> 4, c0 = (lin & 15) * 4;
        uint_t lo = pack2bf(T[c0][r], T[c0 + 1][r]);
        uint_t hi = pack2bf(T[c0 + 2][r], T[c0 + 3][r]);
        *(uint2*)&D[(size_t)(n0 + r) * K + k0 + c0] = make_uint2(lo, hi);
    }
}

// ---------------------------------------------------------------- bf16 MFMA GEMM (BM=128, BN template)
// Double-buffered LDS (R10). MFMA operands SWAPPED -> transposed C-layout:
// lane l15 = output row, quad*4+r = 4 consecutive output cols -> vectorized
// epilogue (b64 bf16 / b128 fp32 stores, float4 bias+residual loads).
// flags: 1=gelu, 2=bf16 out
template<int BNt>
__global__ __launch_bounds__(256)
void gemm_bf16_t(const ushort_t* __restrict__ A, const ushort_t* __restrict__ Bt,
                 const float* __restrict__ bias, const float* __restrict__ residual,
                 void* __restrict__ C, int M, int N, int K, int flags)
{
    __shared__ ushort_t AsL[2][128 * 32];
    __shared__ ushort_t BsL[2][BNt * 32];
    int bm = blockIdx.y * 128;
    int bn = blockIdx.x * BNt;
    int tid = threadIdx.x;
    int lane = tid & 63;
    int wave = tid >> 6;
    int wm = wave >> 1, wn = wave & 1;
    int quad = lane >> 4, l15 = lane & 15;
    constexpr int NJ = BNt / 32;

    int srow = lane >> 2;
    int sg8 = ((lane & 3) ^ ((lane >> 3) & 3)) * 8;
    int fsw = (l15 >> 1) & 3;

    f32x4 acc[4][NJ];
    #pragma unroll
    for (int i = 0; i < 4; ++i)
        #pragma unroll
        for (int j = 0; j < NJ; ++j)
            acc[i][j] = (f32x4){0.f, 0.f, 0.f, 0.f};

    int iters = K / 32;
    llds16(&AsL[0][wave * 512], A + (size_t)(bm + wave * 16 + srow) * K + sg8);
    llds16(&AsL[0][(wave + 4) * 512], A + (size_t)(bm + (wave + 4) * 16 + srow) * K + sg8);
    llds16(&BsL[0][wave * 512], Bt + (size_t)(bn + wave * 16 + srow) * K + sg8);
    if (BNt == 128)
        llds16(&BsL[0][(wave + 4) * 512], Bt + (size_t)(bn + (wave + 4) * 16 + srow) * K + sg8);

    for (int kt = 0; kt < iters; ++kt) {
        int cur = kt & 1;
        __syncthreads();

        bf16x8 af[4], bfr[NJ];
        #pragma unroll
        for (int i = 0; i < 4; ++i)
            af[i] = *(const bf16x8*)&AsL[cur][(wm * 64 + i * 16 + l15) * 32 + ((quad ^ fsw) * 8)];
        #pragma unroll
        for (int j = 0; j < NJ; ++j)
            bfr[j] = *(const bf16x8*)&BsL[cur][(wn * (BNt / 2) + j * 16 + l15) * 32 + ((quad ^ fsw) * 8)];

        if (kt + 1 < iters) {
            int k0 = (kt + 1) * 32;
            int nxt = 1 - cur;
            llds16(&AsL[nxt][wave * 512], A + (size_t)(bm + wave * 16 + srow) * K + k0 + sg8);
            llds16(&AsL[nxt][(wave + 4) * 512], A + (size_t)(bm + (wave + 4) * 16 + srow) * K + k0 + sg8);
            llds16(&BsL[nxt][wave * 512], Bt + (size_t)(bn + wave * 16 + srow) * K + k0 + sg8);
            if (BNt == 128)
                llds16(&BsL[nxt][(wave + 4) * 512], Bt + (size_t)(bn + (wave + 4) * 16 + srow) * K + k0 + sg8);
        }

        // swapped operands: lane = A row (output row), quad*4+r = B row (output col)
        #pragma unroll
        for (int i = 0; i < 4; ++i)
            #pragma unroll
            for (int j = 0; j < NJ; ++j)
                acc[i][j] = MFMA16(bfr[j], af[i], acc[i][j]);
    }

    #pragma unroll
    for (int i = 0; i < 4; ++i) {
        int row = bm + wm * 64 + i * 16 + l15;
        #pragma unroll
        for (int j = 0; j < NJ; ++j) {
            int col = bn + wn * (BNt / 2) + j * 16 + quad * 4;
            float4 bia = *(const float4*)&bias[col];
            float o0 = acc[i][j][0] + bia.x;
            float o1 = acc[i][j][1] + bia.y;
            float o2 = acc[i][j][2] + bia.z;
            float o3 = acc[i][j][3] + bia.w;
            if (flags & 1) {
                o0 = o0 * 0.5f * (1.0f + erff(o0 * 0.70710678f));
                o1 = o1 * 0.5f * (1.0f + erff(o1 * 0.70710678f));
                o2 = o2 * 0.5f * (1.0f + erff(o2 * 0.70710678f));
                o3 = o3 * 0.5f * (1.0f + erff(o3 * 0.70710678f));
            }
            if (residual) {
                float4 rs = *(const float4*)&residual[(size_t)row * N + col];
                o0 += rs.x; o1 += rs.y; o2 += rs.z; o3 += rs.w;
            }
            if (flags & 2) {
                *(uint2*)&((ushort_t*)C)[(size_t)row * N + col] =
                    make_uint2(pack2bf(o0, o1), pack2bf(o2, o3));
            } else {
                *(float4*)&((float*)C)[(size_t)row * N + col] =
                    make_float4(o0, o1, o2, o3);
            }
        }
    }
}

// ---------------------------------------------------------------- dual o-projection
// Two sequential dbuf K-loops, swapped-operand MFMA, vectorized masked epilogue:
// x1 = x + (fg ? vg : (bgwin ? vl : 0)). BM=128, BN=64, K=768.
__global__ __launch_bounds__(256)
void oproj_dual_kernel(const ushort_t* __restrict__ ctxg, const ushort_t* __restrict__ ctxl,
                       const ushort_t* __restrict__ Wg, const ushort_t* __restrict__ Wl,
                       const float* __restrict__ biasg, const float* __restrict__ biasl,
                       const float* __restrict__ x, float* __restrict__ x1,
                       const float* __restrict__ fg, const float* __restrict__ bgw)
{
    __shared__ ushort_t AsL[2][128 * 32];
    __shared__ ushort_t BsL[2][64 * 32];
    int bm = blockIdx.y * 128;
    int bn = blockIdx.x * 64;
    int tid = threadIdx.x;
    int lane = tid & 63;
    int wave = tid >> 6;
    int wm = wave >> 1, wn = wave & 1;
    int quad = lane >> 4, l15 = lane & 15;

    int srow = lane >> 2;
    int sg8 = ((lane & 3) ^ ((lane >> 3) & 3)) * 8;
    int fsw = (l15 >> 1) & 3;
    const int K = Ch, N = Ch, iters = Ch / 32;

    f32x4 accg[4][2], accl[4][2];
    #pragma unroll
    for (int i = 0; i < 4; ++i)
        #pragma unroll
        for (int j = 0; j < 2; ++j) {
            accg[i][j] = (f32x4){0.f, 0.f, 0.f, 0.f};
            accl[i][j] = (f32x4){0.f, 0.f, 0.f, 0.f};
        }

    #pragma unroll
    for (int pass = 0; pass < 2; ++pass) {
        const ushort_t* A = pass ? ctxl : ctxg;
        const ushort_t* Bt = pass ? Wl : Wg;
        if (pass) __syncthreads();
        llds16(&AsL[0][wave * 512], A + (size_t)(bm + wave * 16 + srow) * K + sg8);
        llds16(&AsL[0][(wave + 4) * 512], A + (size_t)(bm + (wave + 4) * 16 + srow) * K + sg8);
        llds16(&BsL[0][wave * 512], Bt + (size_t)(bn + wave * 16 + srow) * K + sg8);

        for (int kt = 0; kt < iters; ++kt) {
            int cur = kt & 1;
            __syncthreads();
            bf16x8 af[4], bfr[2];
            #pragma unroll
            for (int i = 0; i < 4; ++i)
                af[i] = *(const bf16x8*)&AsL[cur][(wm * 64 + i * 16 + l15) * 32 + ((quad ^ fsw) * 8)];
            #pragma unroll
            for (int j = 0; j < 2; ++j)
                bfr[j] = *(const bf16x8*)&BsL[cur][(wn * 32 + j * 16 + l15) * 32 + ((quad ^ fsw) * 8)];
            if (kt + 1 < iters) {
                int k0 = (kt + 1) * 32;
                int nxt = 1 - cur;
                llds16(&AsL[nxt][wave * 512], A + (size_t)(bm + wave * 16 + srow) * K + k0 + sg8);
                llds16(&AsL[nxt][(wave + 4) * 512], A + (size_t)(bm + (wave + 4) * 16 + srow) * K + k0 + sg8);
                llds16(&BsL[nxt][wave * 512], Bt + (size_t)(bn + wave * 16 + srow) * K + k0 + sg8);
            }
            if (pass == 0) {
                #pragma unroll
                for (int i = 0; i < 4; ++i)
                    #pragma unroll
                    for (int j = 0; j < 2; ++j)
                        accg[i][j] = MFMA16(bfr[j], af[i], accg[i][j]);
            } else {
                #pragma unroll
                for (int i = 0; i < 4; ++i)
                    #pragma unroll
                    for (int j = 0; j < 2; ++j)
                        accl[i][j] = MFMA16(bfr[j], af[i], accl[i][j]);
            }
        }
    }

    #pragma unroll
    for (int i = 0; i < 4; ++i) {
        int row = bm + wm * 64 + i * 16 + l15;
        int bb = (row >= Lh) ? 1 : 0;
        int n = row - bb * Lh;
        int ii = n / 48, jj = n % 48;
        float keepg = (fg[row] != 0.0f) ? 1.0f : 0.0f;
        float keepl = (keepg == 0.0f &&
                       bgw[bb * 36 + (ii >> 3) * 6 + (jj >> 3)] != 0.0f) ? 1.0f : 0.0f;
        #pragma unroll
        for (int j = 0; j < 2; ++j) {
            int col = bn + wn * 32 + j * 16 + quad * 4;
            float4 bg4 = *(const float4*)&biasg[col];
            float4 bl4 = *(const float4*)&biasl[col];
            float4 x4 = *(const float4*)&x[(size_t)row * N + col];
            float4 o;
            o.x = x4.x + keepg * (accg[i][j][0] + bg4.x) + keepl * (accl[i][j][0] + bl4.x);
            o.y = x4.y + keepg * (accg[i][j][1] + bg4.y) + keepl * (accl[i][j][1] + bl4.y);
            o.z = x4.z + keepg * (accg[i][j][2] + bg4.z) + keepl * (accl[i][j][2] + bl4.z);
            o.w = x4.w + keepg * (accg[i][j][3] + bg4.w) + keepl * (accl[i][j][3] + bl4.w);
            *(float4*)&x1[(size_t)row * N + col] = o;
        }
    }
}

// ---------------------------------------------------------------- fused attention (global + local)
// S^T trick (R9) + PV operand swap: output lane = q, quad*4+r = 4 consecutive d
// -> b64 O-stores, no lbuf broadcast (l is per-lane q after butterfly reduce).
// R11: global q-tile split 128 -> 64 (2x blocks, occupancy fix for the global
// tail); Ps shrinks to [64][72] -> 5 blocks/CU; exp2-domain softmax.
__device__ __forceinline__ void attn_global_body(
    const ushort_t* __restrict__ QKV, const float* __restrict__ fg,
    ushort_t* __restrict__ O, int tile, int h, int b,
    ushort_t (*Ks)[72], ushort_t (*Vt)[72], ushort_t (*Ps)[72], float* fgs)
{
    int tid = threadIdx.x;
    int lane = tid & 63;
    int wave = tid >> 6;
    int quad = lane >> 4, l15 = lane & 15;

    // 64 queries per block: wave w owns q rows w*16 + l15
    int ql = wave * 16 + l15;
    int tok = tile * 64 + ql;
    bf16x8 aq[2];
    {
        const ushort_t* qbase = QKV + (size_t)(b * Lh + tok) * QS + h * 64;
        #pragma unroll
        for (int step = 0; step < 2; ++step)
            aq[step] = *(const bf16x8*)(qbase + step * 32 + quad * 8);
    }

    float l_part = 0.f;
    f32x4 o_acc[4];
    #pragma unroll
    for (int t4 = 0; t4 < 4; ++t4) o_acc[t4] = (f32x4){0.f, 0.f, 0.f, 0.f};

    uint4 kx[2], vx[2];
    #pragma unroll
    for (int it = 0; it < 2; ++it) {
        int e = tid + it * 256;
        int row = e >> 3, g = e & 7;
        const ushort_t* base = QKV + (size_t)(b * Lh + row) * QS + h * 64 + g * 8;
        kx[it] = *(const uint4*)(base + 768);
        vx[it] = *(const uint4*)(base + 1536);
    }
    float fgn = 0.f;
    if (tid < 64) fgn = fg[b * Lh + tid];

    for (int kt = 0; kt < 36; ++kt) {
        __syncthreads();
        #pragma unroll
        for (int it = 0; it < 2; ++it) {
            int e = tid + it * 256;
            int row = e >> 3, g = e & 7;
            *(uint4*)&Ks[row][g * 8] = kx[it];
            union { uint4 raw; ushort_t us[8]; } vv;
            vv.raw = vx[it];
            int col = row ^ (g << 3);
            #pragma unroll
            for (int j = 0; j < 8; ++j) Vt[g * 8 + j][col] = vv.us[j];
        }
        if (tid < 64) fgs[tid] = (fgn - 1.0f) * MSK2;
        __syncthreads();

        if (kt + 1 < 36) {
            #pragma unroll
            for (int it = 0; it < 2; ++it) {
                int e = tid + it * 256;
                int row = e >> 3, g = e & 7;
                int tok2 = (kt + 1) * 64 + row;
                const ushort_t* base = QKV + (size_t)(b * Lh + tok2) * QS + h * 64 + g * 8;
                kx[it] = *(const uint4*)(base + 768);
                vx[it] = *(const uint4*)(base + 1536);
            }
            if (tid < 64) fgn = fg[b * Lh + (kt + 1) * 64 + tid];
        }

        f32x4 s4[4];
        #pragma unroll
        for (int j4 = 0; j4 < 4; ++j4) s4[j4] = (f32x4){0.f, 0.f, 0.f, 0.f};
        #pragma unroll
        for (int step = 0; step < 2; ++step) {
            bf16x8 bk[4];
            #pragma unroll
            for (int j4 = 0; j4 < 4; ++j4)
                bk[j4] = *(const bf16x8*)&Ks[j4 * 16 + l15][step * 32 + quad * 8];
            #pragma unroll
            for (int j4 = 0; j4 < 4; ++j4)
                s4[j4] = MFMA16(bk[j4], aq[step], s4[j4]);
        }
        int p0 = wave * 16;
        #pragma unroll
        for (int j4 = 0; j4 < 4; ++j4) {
            float4 mb4 = *(const float4*)&fgs[j4 * 16 + quad * 4];
            float e0 = EXP2F(s4[j4][0] * SCL2 + mb4.x);
            float e1 = EXP2F(s4[j4][1] * SCL2 + mb4.y);
            float e2 = EXP2F(s4[j4][2] * SCL2 + mb4.z);
            float e3 = EXP2F(s4[j4][3] * SCL2 + mb4.w);
            l_part += (e0 + e1) + (e2 + e3);
            uint_t a01 = __builtin_amdgcn_perm(__float_as_uint(e1), __float_as_uint(e0), 0x07060302u);
            uint_t a23 = __builtin_amdgcn_perm(__float_as_uint(e3), __float_as_uint(e2), 0x07060302u);
            *(uint2*)&Ps[p0 + l15][j4 * 16 + quad * 4] = make_uint2(a01, a23);
        }
        #pragma unroll
        for (int step = 0; step < 2; ++step) {
            bf16x8 bv[4];
            #pragma unroll
            for (int t4 = 0; t4 < 4; ++t4) {
                int dd = t4 * 16 + l15;
                int cb = ((step * 4 + quad) ^ ((dd >> 3) & 7)) * 8;
                bv[t4] = *(const bf16x8*)&Vt[dd][cb];
            }
            bf16x8 a = *(const bf16x8*)&Ps[p0 + l15][step * 32 + quad * 8];
            #pragma unroll
            for (int t4 = 0; t4 < 4; ++t4)
                o_acc[t4] = MFMA16(bv[t4], a, o_acc[t4]);   // swapped: lane=q
        }
    }

    // l: butterfly reduce across quads -> every lane has full sum for its q=l15
    {
        float v = l_part;
        v += __shfl_xor(v, 16, 64);
        v += __shfl_xor(v, 32, 64);
        float inv = 1.0f / v;
        ushort_t* ob = O + (size_t)(b * Lh + tok) * Ch + h * 64;
        #pragma unroll
        for (int t4 = 0; t4 < 4; ++t4) {
            *(uint2*)&ob[t4 * 16 + quad * 4] =
                make_uint2(pack2bf(o_acc[t4][0] * inv, o_acc[t4][1] * inv),
                           pack2bf(o_acc[t4][2] * inv, o_acc[t4][3] * inv));
        }
    }
}

__device__ __forceinline__ void attn_local_body(
    const ushort_t* __restrict__ QKV, ushort_t* __restrict__ O,
    int tile, int h, int b,
    ushort_t (*Ks)[72], ushort_t (*Vt)[72], ushort_t (*Ps)[72])
{
    int tid = threadIdx.x;
    int lane = tid & 63;
    int wave = tid >> 6;
    int quad = lane >> 4, l15 = lane & 15;
    int wi = tile / 6, wj = tile % 6;

    bf16x8 aq[2];
    {
        int ql = wave * 16 + l15;
        int tok = (wi * 8 + (ql >> 3)) * 48 + wj * 8 + (ql & 7);
        const ushort_t* qbase = QKV + (size_t)(b * Lh + tok) * QS + 2304 + h * 64;
        #pragma unroll
        for (int step = 0; step < 2; ++step)
            aq[step] = *(const bf16x8*)(qbase + step * 32 + quad * 8);
    }

    float l_part = 0.f;
    f32x4 o_acc[4];
    #pragma unroll
    for (int t4 = 0; t4 < 4; ++t4) o_acc[t4] = (f32x4){0.f, 0.f, 0.f, 0.f};

    #pragma unroll
    for (int it = 0; it < 2; ++it) {
        int e = tid + it * 256;
        int row = e >> 3, g = e & 7;
        int tok = (wi * 8 + (row >> 3)) * 48 + wj * 8 + (row & 7);
        const ushort_t* base = QKV + (size_t)(b * Lh + tok) * QS + 2304 + h * 64 + g * 8;
        uint4 kvv = *(const uint4*)(base + 768);
        *(uint4*)&Ks[row][g * 8] = kvv;
        union { uint4 raw; ushort_t us[8]; } vv;
        vv.raw = *(const uint4*)(base + 1536);
        int col = row ^ (g << 3);
        #pragma unroll
        for (int j = 0; j < 8; ++j) Vt[g * 8 + j][col] = vv.us[j];
    }
    __syncthreads();

    f32x4 s4[4];
    #pragma unroll
    for (int j4 = 0; j4 < 4; ++j4) s4[j4] = (f32x4){0.f, 0.f, 0.f, 0.f};
    #pragma unroll
    for (int step = 0; step < 2; ++step) {
        bf16x8 bk[4];
        #pragma unroll
        for (int j4 = 0; j4 < 4; ++j4)
            bk[j4] = *(const bf16x8*)&Ks[j4 * 16 + l15][step * 32 + quad * 8];
        #pragma unroll
        for (int j4 = 0; j4 < 4; ++j4)
            s4[j4] = MFMA16(bk[j4], aq[step], s4[j4]);
    }
    int p0 = wave * 16;
    #pragma unroll
    for (int j4 = 0; j4 < 4; ++j4) {
        float e0 = EXP2F(s4[j4][0] * SCL2);
        float e1 = EXP2F(s4[j4][1] * SCL2);
        float e2 = EXP2F(s4[j4][2] * SCL2);
        float e3 = EXP2F(s4[j4][3] * SCL2);
        l_part += (e0 + e1) + (e2 + e3);
        uint_t a01 = __builtin_amdgcn_perm(__float_as_uint(e1), __float_as_uint(e0), 0x07060302u);
        uint_t a23 = __builtin_amdgcn_perm(__float_as_uint(e3), __float_as_uint(e2), 0x07060302u);
        *(uint2*)&Ps[p0 + l15][j4 * 16 + quad * 4] = make_uint2(a01, a23);
    }
    #pragma unroll
    for (int step = 0; step < 2; ++step) {
        bf16x8 bv[4];
        #pragma unroll
        for (int t4 = 0; t4 < 4; ++t4) {
            int dd = t4 * 16 + l15;
            int cb = ((step * 4 + quad) ^ ((dd >> 3) & 7)) * 8;
            bv[t4] = *(const bf16x8*)&Vt[dd][cb];
        }
        bf16x8 a = *(const bf16x8*)&Ps[p0 + l15][step * 32 + quad * 8];
        #pragma unroll
        for (int t4 = 0; t4 < 4; ++t4)
            o_acc[t4] = MFMA16(bv[t4], a, o_acc[t4]);   // swapped: lane=q
    }

    {
        float v = l_part;
        v += __shfl_xor(v, 16, 64);
        v += __shfl_xor(v, 32, 64);
        float inv = 1.0f / v;
        int ql = wave * 16 + l15;
        int tok = (wi * 8 + (ql >> 3)) * 48 + wj * 8 + (ql & 7);
        ushort_t* ob = O + (size_t)(b * Lh + tok) * Ch + h * 64;
        #pragma unroll
        for (int t4 = 0; t4 < 4; ++t4) {
            *(uint2*)&ob[t4 * 16 + quad * 4] =
                make_uint2(pack2bf(o_acc[t4][0] * inv, o_acc[t4][1] * inv),
                           pack2bf(o_acc[t4][2] * inv, o_acc[t4][3] * inv));
        }
    }
}

__global__ __launch_bounds__(256)
void attn_fused_kernel(const ushort_t* __restrict__ QKV, const float* __restrict__ fg,
                       ushort_t* __restrict__ ctxg, ushort_t* __restrict__ ctxl)
{
    __shared__ ushort_t Ks[64][72];
    __shared__ ushort_t Vt[64][72];
    __shared__ ushort_t Ps[64][72];
    __shared__ float fgs[64];

    int bid = blockIdx.x;
    if (bid < 864) {
        // XCD-aware swizzle within the global range: 108 consecutive logical
        // blocks (= 3 complete (b,h) K/V groups, 1.77 MB) per XCD -> K/V stays
        // L2-resident; globals stay balanced across all 8 XCDs.
        int gid = (bid & 7) * 108 + (bid >> 3);
        int tile = gid % 36;
        int h = (gid / 36) % NHh;
        int b = gid / 432;
        attn_global_body(QKV, fg, ctxg, tile, h, b, Ks, Vt, Ps, fgs);
    } else {
        int rr = bid - 864;
        int lid = (rr & 7) * 108 + (rr >> 3);
        int tile = lid % 36;
        int h = (lid / 36) % NHh;
        int b = lid / 432;
        attn_local_body(QKV, ctxl, tile, h, b, Ks, Vt, Ps);
    }
}

// ---------------------------------------------------------------- launch
extern "C" void kernel_launch(void* const* d_in, const int* in_sizes, int n_in,
                              void* d_out, int out_size, void* d_ws, size_t ws_size,
                              hipStream_t stream)
{
    const float* x       = (const float*)d_in[0];
    const float* mask    = (const float*)d_in[1];
    const float* w_qkv_g = (const float*)d_in[2];
    const float* b_qkv_g = (const float*)d_in[3];
    const float* w_o_g   = (const float*)d_in[4];
    const float* b_o_g   = (const float*)d_in[5];
    const float* w_qkv_l = (const float*)d_in[6];
    const float* b_qkv_l = (const float*)d_in[7];
    const float* w_o_l   = (const float*)d_in[8];
    const float* b_o_l   = (const float*)d_in[9];
    const float* ln1_w   = (const float*)d_in[10];
    const float* ln1_b   = (const float*)d_in[11];
    const float* ln2_w   = (const float*)d_in[12];
    const float* ln2_b   = (const float*)d_in[13];
    const float* w_fc1   = (const float*)d_in[14];
    const float* b_fc1   = (const float*)d_in[15];
    const float* w_fc2   = (const float*)d_in[16];
    const float* b_fc2   = (const float*)d_in[17];
    float* out = (float*)d_out;

    const size_t U = (size_t)Bh * Lh * Ch;           // 3,538,944
    char* p = (char*)d_ws;
    ushort_t* qkvb = (ushort_t*)p;        p += (size_t)4608 * 4608 * 2;  // [4608][4608] bf16
    ushort_t* midb = qkvb;                                               // [4608][3072] aliases
    ushort_t* ctxg = (ushort_t*)p;        p += U * 2;
    ushort_t* ctxl = (ushort_t*)p;        p += U * 2;
    ushort_t* xnb  = (ushort_t*)p;        p += U * 2;
    float*    x1   = (float*)p;           p += U * 4;
    ushort_t* wtq  = (ushort_t*)p;        p += (size_t)4608 * 768 * 2;   // qkv g|l concat
    ushort_t* wt_o_g = (ushort_t*)p;      p += (size_t)768 * 768 * 2;
    ushort_t* wt_o_l = (ushort_t*)p;      p += (size_t)768 * 768 * 2;
    ushort_t* wt_fc1 = (ushort_t*)p;      p += (size_t)3072 * 768 * 2;
    ushort_t* wt_fc2 = (ushort_t*)p;      p += (size_t)768 * 3072 * 2;
    float*    biasq  = (float*)p;         p += 4608 * 4;
    float*    fg     = (float*)p;         p += Bh * Lh * 4;
    float*    bgw    = (float*)p;

    const int Mrows = Bh * Lh;                   // 4608
    dim3 blk(256);

    hipMemcpyAsync(biasq, b_qkv_g, 2304 * sizeof(float), hipMemcpyDeviceToDevice, stream);
    hipMemcpyAsync(biasq + 2304, b_qkv_l, 2304 * sizeof(float), hipMemcpyDeviceToDevice, stream);

    transpose_all_kernel<<<2304, blk, 0, stream>>>(
        w_qkv_g, w_qkv_l, w_o_g, w_o_l, w_fc1, w_fc2,
        wtq, wt_o_g, wt_o_l, wt_fc1, wt_fc2);

    layernorm_bf16_kernel<<<Mrows, blk, 0, stream>>>(x, ln1_w, ln1_b, xnb);
    mask_kernel<<<72, dim3(64), 0, stream>>>(mask, fg, bgw);

    // fused QKV GEMM for both branches (N=4608)
    gemm_bf16_t<128><<<dim3(4608 / 128, Mrows / 128), blk, 0, stream>>>(
        xnb, wtq, biasq, nullptr, qkvb, Mrows, 4608, Ch, 2);

    // fused attention: 864 global (64-q tiles) + 864 local blocks
    attn_fused_kernel<<<1728, blk, 0, stream>>>(qkvb, fg, ctxg, ctxl);

    // dual masked o-projection -> x1 (one dispatch)
    oproj_dual_kernel<<<dim3(Ch / 64, Mrows / 128), blk, 0, stream>>>(
        ctxg, ctxl, wt_o_g, wt_o_l, b_o_g, b_o_l, x, x1, fg, bgw);

    layernorm_bf16_kernel<<<Mrows, blk, 0, stream>>>(x1, ln2_w, ln2_b, xnb);

    // MLP
    gemm_bf16_t<128><<<dim3(3072 / 128, Mrows / 128), blk, 0, stream>>>(
        xnb, wt_fc1, b_fc1, nullptr, midb, Mrows, 3072, Ch, 1 | 2);
    gemm_bf16_t<64><<<dim3(Ch / 64, Mrows / 128), blk, 0, stream>>>(
        midb, wt_fc2, b_fc2, x1, out, Mrows, Ch, 3072, 0);
}

// Round 3
// 410.002 us; speedup vs baseline: 1.0470x; 1.0470x over previous
//
#include <hip/hip_runtime.h>
#include <math.h>

#define Lh 2304
#define Ch 768
#define NHh 12
#define Bh 2
#define QS 4608   // row stride of fused qkv activation buffer (global q|k|v, local q|k|v)

typedef unsigned short ushort_t;
typedef unsigned int uint_t;
typedef __attribute__((ext_vector_type(8))) short bf16x8;
typedef __attribute__((ext_vector_type(4))) float f32x4;
#define MFMA16(a, b, c) __builtin_amdgcn_mfma_f32_16x16x32_bf16(a, b, c, 0, 0, 0)

// softmax in exp2 domain: exp(s*0.125 + m) == exp2(s*SCL2 + m*log2e)  (R1-validated)
#define SCL2 0.18033688f        // 0.125 * log2(e)
#define MSK2 1.4426950e9f       // 1e9  * log2(e)
#if __has_builtin(__builtin_amdgcn_exp2f)
#define EXP2F(x) __builtin_amdgcn_exp2f(x)
#else
#define EXP2F(x) exp2f(x)
#endif

__device__ __forceinline__ ushort_t f2bf(float f) {
    union { float f; uint_t u; } v; v.f = f;
    uint_t u = v.u + 0x7fffu + ((v.u >> 16) & 1u);   // RNE
    return (ushort_t)(u >> 16);
}
// pack 2 fp32 -> 2 bf16 (RNE) into one u32
__device__ __forceinline__ uint_t pack2bf(float a, float b) {
    return (uint_t)f2bf(a) | ((uint_t)f2bf(b) << 16);
}

// async global->LDS, 16B/lane, dest = wave-uniform base + lane*16
__device__ __forceinline__ void llds16(ushort_t* dst, const ushort_t* src) {
    __builtin_amdgcn_global_load_lds(
        (__attribute__((address_space(1))) void*)(const_cast<ushort_t*>(src)),
        (__attribute__((address_space(3))) void*)dst, 16, 0, 0);
}

// ---------------------------------------------------------------- layernorm (fp32 in, bf16 out)
__global__ __launch_bounds__(256)
void layernorm_bf16_kernel(const float* __restrict__ x, const float* __restrict__ w,
                           const float* __restrict__ b, ushort_t* __restrict__ y)
{
    int row = blockIdx.x;
    int tid = threadIdx.x;
    const float* xr = x + (size_t)row * Ch;
    float v0 = xr[tid], v1 = xr[tid + 256], v2 = xr[tid + 512];
    __shared__ float red[256];
    red[tid] = v0 + v1 + v2;
    __syncthreads();
    for (int st = 128; st > 0; st >>= 1) {
        if (tid < st) red[tid] += red[tid + st];
        __syncthreads();
    }
    float mean = red[0] * (1.0f / 768.0f);
    __syncthreads();
    float d0 = v0 - mean, d1 = v1 - mean, d2 = v2 - mean;
    red[tid] = d0 * d0 + d1 * d1 + d2 * d2;
    __syncthreads();
    for (int st = 128; st > 0; st >>= 1) {
        if (tid < st) red[tid] += red[tid + st];
        __syncthreads();
    }
    float rstd = rsqrtf(red[0] * (1.0f / 768.0f) + 1e-6f);
    ushort_t* yr = y + (size_t)row * Ch;
    yr[tid]       = f2bf(d0 * rstd * w[tid]       + b[tid]);
    yr[tid + 256] = f2bf(d1 * rstd * w[tid + 256] + b[tid + 256]);
    yr[tid + 512] = f2bf(d2 * rstd * w[tid + 512] + b[tid + 512]);
}

// ---------------------------------------------------------------- fused mask kernel
__global__ __launch_bounds__(64)
void mask_kernel(const float* __restrict__ mask, float* __restrict__ fg,
                 float* __restrict__ bgw)
{
    int win = blockIdx.x;            // 0..71
    int b = win / 36, w = win % 36;
    int wi = w / 6, wj = w % 6;
    int lane = threadIdx.x;          // 64
    int i = wi * 8 + (lane >> 3), j = wj * 8 + (lane & 7);
    const float* mb = mask + (size_t)b * 192 * 192 + (size_t)(i * 4) * 192 + j * 4;
    float s = 0.0f;
    #pragma unroll
    for (int di = 0; di < 4; ++di) {
        float4 v = *(const float4*)(mb + (size_t)di * 192);
        s += v.x + v.y + v.z + v.w;
    }
    float f = (s * (1.0f / 16.0f) > 0.4f) ? 1.0f : 0.0f;
    fg[b * Lh + i * 48 + j] = f;
    unsigned long long bg = __ballot(f == 0.0f);
    if (lane == 0) bgw[win] = bg ? 1.0f : 0.0f;
}

// ---------------------------------------------------------------- batched weight cast+transpose
__global__ __launch_bounds__(256)
void transpose_all_kernel(const float* __restrict__ w_qkv_g, const float* __restrict__ w_qkv_l,
                          const float* __restrict__ w_o_g, const float* __restrict__ w_o_l,
                          const float* __restrict__ w_fc1, const float* __restrict__ w_fc2,
                          ushort_t* __restrict__ wtq, ushort_t* __restrict__ wt_o_g,
                          ushort_t* __restrict__ wt_o_l, ushort_t* __restrict__ wt_fc1,
                          ushort_t* __restrict__ wt_fc2)
{
    int blk = blockIdx.x;
    const float* W; ushort_t* D; int K, N, nx, bx;
    const size_t CC = (size_t)Ch * Ch;
    if (blk < 432)       { int t = blk / 144; bx = blk % 144;
                           W = w_qkv_g + t * CC; D = wtq + t * CC; K = 768; N = 768; nx = 12; }
    else if (blk < 864)  { int r = blk - 432; int t = r / 144; bx = r % 144;
                           W = w_qkv_l + t * CC; D = wtq + (size_t)2304 * 768 + t * CC;
                           K = 768; N = 768; nx = 12; }
    else if (blk < 1008) { bx = blk - 864;  W = w_o_g; D = wt_o_g; K = 768; N = 768; nx = 12; }
    else if (blk < 1152) { bx = blk - 1008; W = w_o_l; D = wt_o_l; K = 768; N = 768; nx = 12; }
    else if (blk < 1728) { bx = blk - 1152; W = w_fc1; D = wt_fc1; K = 768; N = 3072; nx = 48; }
    else                 { bx = blk - 1728; W = w_fc2; D = wt_fc2; K = 3072; N = 768; nx = 12; }
    int n0 = (bx % nx) * 64;
    int k0 = (bx / nx) * 64;
    int tid = threadIdx.x;
    __shared__ float T[64][65];
    #pragma unroll
    for (int i = 0; i < 16; ++i) {
        int lin = i * 256 + tid;
        int r = lin >> 6, c = lin & 63;
        T[r][c] = W[(size_t)(k0 + r) * N + n0 + c];
    }
    __syncthreads();
    // vectorized: each unit = (n-row r, 4 consecutive k) -> one b64 store
    #pragma unroll
    for (int i = 0; i < 4; ++i) {
        int lin = i * 256 + tid;          // 0..1023
        int r = lin >> 4, c0 = (lin & 15) * 4;
        uint_t lo = pack2bf(T[c0][r], T[c0 + 1][r]);
        uint_t hi = pack2bf(T[c0 + 2][r], T[c0 + 3][r]);
        *(uint2*)&D[(size_t)(n0 + r) * K + k0 + c0] = make_uint2(lo, hi);
    }
}

// ---------------------------------------------------------------- bf16 MFMA GEMM (BM=128, BN template)
// flags: 1=gelu, 2=bf16 out
template<int BNt>
__global__ __launch_bounds__(256)
void gemm_bf16_t(const ushort_t* __restrict__ A, const ushort_t* __restrict__ Bt,
                 const float* __restrict__ bias, const float* __restrict__ residual,
                 void* __restrict__ C, int M, int N, int K, int flags)
{
    __shared__ ushort_t AsL[2][128 * 32];
    __shared__ ushort_t BsL[2][BNt * 32];
    int bm = blockIdx.y * 128;
    int bn = blockIdx.x * BNt;
    int tid = threadIdx.x;
    int lane = tid & 63;
    int wave = tid >> 6;
    int wm = wave >> 1, wn = wave & 1;
    int quad = lane >> 4, l15 = lane & 15;
    constexpr int NJ = BNt / 32;

    int srow = lane >> 2;
    int sg8 = ((lane & 3) ^ ((lane >> 3) & 3)) * 8;
    int fsw = (l15 >> 1) & 3;

    f32x4 acc[4][NJ];
    #pragma unroll
    for (int i = 0; i < 4; ++i)
        #pragma unroll
        for (int j = 0; j < NJ; ++j)
            acc[i][j] = (f32x4){0.f, 0.f, 0.f, 0.f};

    int iters = K / 32;
    llds16(&AsL[0][wave * 512], A + (size_t)(bm + wave * 16 + srow) * K + sg8);
    llds16(&AsL[0][(wave + 4) * 512], A + (size_t)(bm + (wave + 4) * 16 + srow) * K + sg8);
    llds16(&BsL[0][wave * 512], Bt + (size_t)(bn + wave * 16 + srow) * K + sg8);
    if (BNt == 128)
        llds16(&BsL[0][(wave + 4) * 512], Bt + (size_t)(bn + (wave + 4) * 16 + srow) * K + sg8);

    for (int kt = 0; kt < iters; ++kt) {
        int cur = kt & 1;
        __syncthreads();

        bf16x8 af[4], bfr[NJ];
        #pragma unroll
        for (int i = 0; i < 4; ++i)
            af[i] = *(const bf16x8*)&AsL[cur][(wm * 64 + i * 16 + l15) * 32 + ((quad ^ fsw) * 8)];
        #pragma unroll
        for (int j = 0; j < NJ; ++j)
            bfr[j] = *(const bf16x8*)&BsL[cur][(wn * (BNt / 2) + j * 16 + l15) * 32 + ((quad ^ fsw) * 8)];

        if (kt + 1 < iters) {
            int k0 = (kt + 1) * 32;
            int nxt = 1 - cur;
            llds16(&AsL[nxt][wave * 512], A + (size_t)(bm + wave * 16 + srow) * K + k0 + sg8);
            llds16(&AsL[nxt][(wave + 4) * 512], A + (size_t)(bm + (wave + 4) * 16 + srow) * K + k0 + sg8);
            llds16(&BsL[nxt][wave * 512], Bt + (size_t)(bn + wave * 16 + srow) * K + k0 + sg8);
            if (BNt == 128)
                llds16(&BsL[nxt][(wave + 4) * 512], Bt + (size_t)(bn + (wave + 4) * 16 + srow) * K + k0 + sg8);
        }

        // swapped operands: lane = A row (output row), quad*4+r = B row (output col)
        #pragma unroll
        for (int i = 0; i < 4; ++i)
            #pragma unroll
            for (int j = 0; j < NJ; ++j)
                acc[i][j] = MFMA16(bfr[j], af[i], acc[i][j]);
    }

    #pragma unroll
    for (int i = 0; i < 4; ++i) {
        int row = bm + wm * 64 + i * 16 + l15;
        #pragma unroll
        for (int j = 0; j < NJ; ++j) {
            int col = bn + wn * (BNt / 2) + j * 16 + quad * 4;
            float4 bia = *(const float4*)&bias[col];
            float o0 = acc[i][j][0] + bia.x;
            float o1 = acc[i][j][1] + bia.y;
            float o2 = acc[i][j][2] + bia.z;
            float o3 = acc[i][j][3] + bia.w;
            if (flags & 1) {
                o0 = o0 * 0.5f * (1.0f + erff(o0 * 0.70710678f));
                o1 = o1 * 0.5f * (1.0f + erff(o1 * 0.70710678f));
                o2 = o2 * 0.5f * (1.0f + erff(o2 * 0.70710678f));
                o3 = o3 * 0.5f * (1.0f + erff(o3 * 0.70710678f));
            }
            if (residual) {
                float4 rs = *(const float4*)&residual[(size_t)row * N + col];
                o0 += rs.x; o1 += rs.y; o2 += rs.z; o3 += rs.w;
            }
            if (flags & 2) {
                *(uint2*)&((ushort_t*)C)[(size_t)row * N + col] =
                    make_uint2(pack2bf(o0, o1), pack2bf(o2, o3));
            } else {
                *(float4*)&((float*)C)[(size_t)row * N + col] =
                    make_float4(o0, o1, o2, o3);
            }
        }
    }
}

// ---------------------------------------------------------------- dual o-projection
__global__ __launch_bounds__(256)
void oproj_dual_kernel(const ushort_t* __restrict__ ctxg, const ushort_t* __restrict__ ctxl,
                       const ushort_t* __restrict__ Wg, const ushort_t* __restrict__ Wl,
                       const float* __restrict__ biasg, const float* __restrict__ biasl,
                       const float* __restrict__ x, float* __restrict__ x1,
                       const float* __restrict__ fg, const float* __restrict__ bgw)
{
    __shared__ ushort_t AsL[2][128 * 32];
    __shared__ ushort_t BsL[2][64 * 32];
    int bm = blockIdx.y * 128;
    int bn = blockIdx.x * 64;
    int tid = threadIdx.x;
    int lane = tid & 63;
    int wave = tid >> 6;
    int wm = wave >> 1, wn = wave & 1;
    int quad = lane >> 4, l15 = lane & 15;

    int srow = lane >> 2;
    int sg8 = ((lane & 3) ^ ((lane >> 3) & 3)) * 8;
    int fsw = (l15 >> 1) & 3;
    const int K = Ch, N = Ch, iters = Ch / 32;

    f32x4 accg[4][2], accl[4][2];
    #pragma unroll
    for (int i = 0; i < 4; ++i)
        #pragma unroll
        for (int j = 0; j < 2; ++j) {
            accg[i][j] = (f32x4){0.f, 0.f, 0.f, 0.f};
            accl[i][j] = (f32x4){0.f, 0.f, 0.f, 0.f};
        }

    #pragma unroll
    for (int pass = 0; pass < 2; ++pass) {
        const ushort_t* A = pass ? ctxl : ctxg;
        const ushort_t* Bt = pass ? Wl : Wg;
        if (pass) __syncthreads();
        llds16(&AsL[0][wave * 512], A + (size_t)(bm + wave * 16 + srow) * K + sg8);
        llds16(&AsL[0][(wave + 4) * 512], A + (size_t)(bm + (wave + 4) * 16 + srow) * K + sg8);
        llds16(&BsL[0][wave * 512], Bt + (size_t)(bn + wave * 16 + srow) * K + sg8);

        for (int kt = 0; kt < iters; ++kt) {
            int cur = kt & 1;
            __syncthreads();
            bf16x8 af[4], bfr[2];
            #pragma unroll
            for (int i = 0; i < 4; ++i)
                af[i] = *(const bf16x8*)&AsL[cur][(wm * 64 + i * 16 + l15) * 32 + ((quad ^ fsw) * 8)];
            #pragma unroll
            for (int j = 0; j < 2; ++j)
                bfr[j] = *(const bf16x8*)&BsL[cur][(wn * 32 + j * 16 + l15) * 32 + ((quad ^ fsw) * 8)];
            if (kt + 1 < iters) {
                int k0 = (kt + 1) * 32;
                int nxt = 1 - cur;
                llds16(&AsL[nxt][wave * 512], A + (size_t)(bm + wave * 16 + srow) * K + k0 + sg8);
                llds16(&AsL[nxt][(wave + 4) * 512], A + (size_t)(bm + (wave + 4) * 16 + srow) * K + k0 + sg8);
                llds16(&BsL[nxt][wave * 512], Bt + (size_t)(bn + wave * 16 + srow) * K + k0 + sg8);
            }
            if (pass == 0) {
                #pragma unroll
                for (int i = 0; i < 4; ++i)
                    #pragma unroll
                    for (int j = 0; j < 2; ++j)
                        accg[i][j] = MFMA16(bfr[j], af[i], accg[i][j]);
            } else {
                #pragma unroll
                for (int i = 0; i < 4; ++i)
                    #pragma unroll
                    for (int j = 0; j < 2; ++j)
                        accl[i][j] = MFMA16(bfr[j], af[i], accl[i][j]);
            }
        }
    }

    #pragma unroll
    for (int i = 0; i < 4; ++i) {
        int row = bm + wm * 64 + i * 16 + l15;
        int bb = (row >= Lh) ? 1 : 0;
        int n = row - bb * Lh;
        int ii = n / 48, jj = n % 48;
        float keepg = (fg[row] != 0.0f) ? 1.0f : 0.0f;
        float keepl = (keepg == 0.0f &&
                       bgw[bb * 36 + (ii >> 3) * 6 + (jj >> 3)] != 0.0f) ? 1.0f : 0.0f;
        #pragma unroll
        for (int j = 0; j < 2; ++j) {
            int col = bn + wn * 32 + j * 16 + quad * 4;
            float4 bg4 = *(const float4*)&biasg[col];
            float4 bl4 = *(const float4*)&biasl[col];
            float4 x4 = *(const float4*)&x[(size_t)row * N + col];
            float4 o;
            o.x = x4.x + keepg * (accg[i][j][0] + bg4.x) + keepl * (accl[i][j][0] + bl4.x);
            o.y = x4.y + keepg * (accg[i][j][1] + bg4.y) + keepl * (accl[i][j][1] + bl4.y);
            o.z = x4.z + keepg * (accg[i][j][2] + bg4.z) + keepl * (accl[i][j][2] + bl4.z);
            o.w = x4.w + keepg * (accg[i][j][3] + bg4.w) + keepl * (accl[i][j][3] + bl4.w);
            *(float4*)&x1[(size_t)row * N + col] = o;
        }
    }
}

// ---------------------------------------------------------------- fused attention (global + local)
// R13: split-KV for the global branch. Each global block processes HALF the
// keys (18 kt) for a 128-q tile, writing unnormalized (o, l) partials in f32.
// Total staging work unchanged (864x18 == 432x36); resident waves during the
// global phase double (6.8 -> 13.5 waves/CU). Merge kernel combines halves.
__device__ __forceinline__ void attn_global_body(
    const ushort_t* __restrict__ QKV, const float* __restrict__ fg,
    float* __restrict__ Opart, float* __restrict__ Lpart,
    int tile, int h, int b, int half,
    ushort_t (*Ks)[72], ushort_t (*Vt)[72], ushort_t (*Ps)[72], float* fgs)
{
    int tid = threadIdx.x;
    int lane = tid & 63;
    int wave = tid >> 6;
    int quad = lane >> 4, l15 = lane & 15;
    int kb0 = half * 1152;            // key-token base for this half

    bf16x8 aq[2][2];
    #pragma unroll
    for (int s = 0; s < 2; ++s) {
        int ql = wave * 32 + s * 16 + l15;
        int tok = tile * 128 + ql;
        const ushort_t* qbase = QKV + (size_t)(b * Lh + tok) * QS + h * 64;
        #pragma unroll
        for (int step = 0; step < 2; ++step)
            aq[s][step] = *(const bf16x8*)(qbase + step * 32 + quad * 8);
    }

    float l_part[2] = {0.f, 0.f};
    f32x4 o_acc[2][4];
    #pragma unroll
    for (int s = 0; s < 2; ++s)
        #pragma unroll
        for (int t4 = 0; t4 < 4; ++t4) o_acc[s][t4] = (f32x4){0.f, 0.f, 0.f, 0.f};

    uint4 kx[2], vx[2];
    #pragma unroll
    for (int it = 0; it < 2; ++it) {
        int e = tid + it * 256;
        int row = e >> 3, g = e & 7;
        const ushort_t* base = QKV + (size_t)(b * Lh + kb0 + row) * QS + h * 64 + g * 8;
        kx[it] = *(const uint4*)(base + 768);
        vx[it] = *(const uint4*)(base + 1536);
    }
    float fgn = 0.f;
    if (tid < 64) fgn = fg[b * Lh + kb0 + tid];

    for (int kt = 0; kt < 18; ++kt) {
        __syncthreads();
        #pragma unroll
        for (int it = 0; it < 2; ++it) {
            int e = tid + it * 256;
            int row = e >> 3, g = e & 7;
            *(uint4*)&Ks[row][g * 8] = kx[it];
            union { uint4 raw; ushort_t us[8]; } vv;
            vv.raw = vx[it];
            int col = row ^ (g << 3);
            #pragma unroll
            for (int j = 0; j < 8; ++j) Vt[g * 8 + j][col] = vv.us[j];
        }
        if (tid < 64) fgs[tid] = (fgn - 1.0f) * MSK2;
        __syncthreads();

        if (kt + 1 < 18) {
            #pragma unroll
            for (int it = 0; it < 2; ++it) {
                int e = tid + it * 256;
                int row = e >> 3, g = e & 7;
                int tok2 = kb0 + (kt + 1) * 64 + row;
                const ushort_t* base = QKV + (size_t)(b * Lh + tok2) * QS + h * 64 + g * 8;
                kx[it] = *(const uint4*)(base + 768);
                vx[it] = *(const uint4*)(base + 1536);
            }
            if (tid < 64) fgn = fg[b * Lh + kb0 + (kt + 1) * 64 + tid];
        }

        f32x4 s4[2][4];
        #pragma unroll
        for (int s = 0; s < 2; ++s)
            #pragma unroll
            for (int j4 = 0; j4 < 4; ++j4) s4[s][j4] = (f32x4){0.f, 0.f, 0.f, 0.f};
        #pragma unroll
        for (int step = 0; step < 2; ++step) {
            bf16x8 bk[4];
            #pragma unroll
            for (int j4 = 0; j4 < 4; ++j4)
                bk[j4] = *(const bf16x8*)&Ks[j4 * 16 + l15][step * 32 + quad * 8];
            #pragma unroll
            for (int s = 0; s < 2; ++s)
                #pragma unroll
                for (int j4 = 0; j4 < 4; ++j4)
                    s4[s][j4] = MFMA16(bk[j4], aq[s][step], s4[s][j4]);
        }
        #pragma unroll
        for (int s = 0; s < 2; ++s) {
            int p0 = wave * 32 + s * 16;
            #pragma unroll
            for (int j4 = 0; j4 < 4; ++j4) {
                float4 mb4 = *(const float4*)&fgs[j4 * 16 + quad * 4];
                float e0 = EXP2F(s4[s][j4][0] * SCL2 + mb4.x);
                float e1 = EXP2F(s4[s][j4][1] * SCL2 + mb4.y);
                float e2 = EXP2F(s4[s][j4][2] * SCL2 + mb4.z);
                float e3 = EXP2F(s4[s][j4][3] * SCL2 + mb4.w);
                l_part[s] += (e0 + e1) + (e2 + e3);
                uint_t a01 = __builtin_amdgcn_perm(__float_as_uint(e1), __float_as_uint(e0), 0x07060302u);
                uint_t a23 = __builtin_amdgcn_perm(__float_as_uint(e3), __float_as_uint(e2), 0x07060302u);
                *(uint2*)&Ps[p0 + l15][j4 * 16 + quad * 4] = make_uint2(a01, a23);
            }
        }
        #pragma unroll
        for (int step = 0; step < 2; ++step) {
            bf16x8 bv[4];
            #pragma unroll
            for (int t4 = 0; t4 < 4; ++t4) {
                int dd = t4 * 16 + l15;
                int cb = ((step * 4 + quad) ^ ((dd >> 3) & 7)) * 8;
                bv[t4] = *(const bf16x8*)&Vt[dd][cb];
            }
            #pragma unroll
            for (int s = 0; s < 2; ++s) {
                int p0 = wave * 32 + s * 16;
                bf16x8 a = *(const bf16x8*)&Ps[p0 + l15][step * 32 + quad * 8];
                #pragma unroll
                for (int t4 = 0; t4 < 4; ++t4)
                    o_acc[s][t4] = MFMA16(bv[t4], a, o_acc[s][t4]);   // swapped: lane=q
            }
        }
    }

    // partial outputs: unnormalized o (f32) + l per (q,h)
    #pragma unroll
    for (int s = 0; s < 2; ++s) {
        float v = l_part[s];
        v += __shfl_xor(v, 16, 64);
        v += __shfl_xor(v, 32, 64);
        int ql = wave * 32 + s * 16 + l15;
        int tok = tile * 128 + ql;
        float* op = Opart + ((size_t)half * 4608 + b * Lh + tok) * Ch + h * 64;
        #pragma unroll
        for (int t4 = 0; t4 < 4; ++t4)
            *(f32x4*)&op[t4 * 16 + quad * 4] = o_acc[s][t4];
        if (quad == 0)
            Lpart[((size_t)half * 4608 + b * Lh + tok) * NHh + h] = v;
    }
}

__device__ __forceinline__ void attn_local_body(
    const ushort_t* __restrict__ QKV, ushort_t* __restrict__ O,
    int tile, int h, int b,
    ushort_t (*Ks)[72], ushort_t (*Vt)[72], ushort_t (*Ps)[72])
{
    int tid = threadIdx.x;
    int lane = tid & 63;
    int wave = tid >> 6;
    int quad = lane >> 4, l15 = lane & 15;
    int wi = tile / 6, wj = tile % 6;

    bf16x8 aq[2];
    {
        int ql = wave * 16 + l15;
        int tok = (wi * 8 + (ql >> 3)) * 48 + wj * 8 + (ql & 7);
        const ushort_t* qbase = QKV + (size_t)(b * Lh + tok) * QS + 2304 + h * 64;
        #pragma unroll
        for (int step = 0; step < 2; ++step)
            aq[step] = *(const bf16x8*)(qbase + step * 32 + quad * 8);
    }

    float l_part = 0.f;
    f32x4 o_acc[4];
    #pragma unroll
    for (int t4 = 0; t4 < 4; ++t4) o_acc[t4] = (f32x4){0.f, 0.f, 0.f, 0.f};

    #pragma unroll
    for (int it = 0; it < 2; ++it) {
        int e = tid + it * 256;
        int row = e >> 3, g = e & 7;
        int tok = (wi * 8 + (row >> 3)) * 48 + wj * 8 + (row & 7);
        const ushort_t* base = QKV + (size_t)(b * Lh + tok) * QS + 2304 + h * 64 + g * 8;
        uint4 kvv = *(const uint4*)(base + 768);
        *(uint4*)&Ks[row][g * 8] = kvv;
        union { uint4 raw; ushort_t us[8]; } vv;
        vv.raw = *(const uint4*)(base + 1536);
        int col = row ^ (g << 3);
        #pragma unroll
        for (int j = 0; j < 8; ++j) Vt[g * 8 + j][col] = vv.us[j];
    }
    __syncthreads();

    f32x4 s4[4];
    #pragma unroll
    for (int j4 = 0; j4 < 4; ++j4) s4[j4] = (f32x4){0.f, 0.f, 0.f, 0.f};
    #pragma unroll
    for (int step = 0; step < 2; ++step) {
        bf16x8 bk[4];
        #pragma unroll
        for (int j4 = 0; j4 < 4; ++j4)
            bk[j4] = *(const bf16x8*)&Ks[j4 * 16 + l15][step * 32 + quad * 8];
        #pragma unroll
        for (int j4 = 0; j4 < 4; ++j4)
            s4[j4] = MFMA16(bk[j4], aq[step], s4[j4]);
    }
    int p0 = wave * 16;
    #pragma unroll
    for (int j4 = 0; j4 < 4; ++j4) {
        float e0 = EXP2F(s4[j4][0] * SCL2);
        float e1 = EXP2F(s4[j4][1] * SCL2);
        float e2 = EXP2F(s4[j4][2] * SCL2);
        float e3 = EXP2F(s4[j4][3] * SCL2);
        l_part += (e0 + e1) + (e2 + e3);
        uint_t a01 = __builtin_amdgcn_perm(__float_as_uint(e1), __float_as_uint(e0), 0x07060302u);
        uint_t a23 = __builtin_amdgcn_perm(__float_as_uint(e3), __float_as_uint(e2), 0x07060302u);
        *(uint2*)&Ps[p0 + l15][j4 * 16 + quad * 4] = make_uint2(a01, a23);
    }
    #pragma unroll
    for (int step = 0; step < 2; ++step) {
        bf16x8 bv[4];
        #pragma unroll
        for (int t4 = 0; t4 < 4; ++t4) {
            int dd = t4 * 16 + l15;
            int cb = ((step * 4 + quad) ^ ((dd >> 3) & 7)) * 8;
            bv[t4] = *(const bf16x8*)&Vt[dd][cb];
        }
        bf16x8 a = *(const bf16x8*)&Ps[p0 + l15][step * 32 + quad * 8];
        #pragma unroll
        for (int t4 = 0; t4 < 4; ++t4)
            o_acc[t4] = MFMA16(bv[t4], a, o_acc[t4]);   // swapped: lane=q
    }

    {
        float v = l_part;
        v += __shfl_xor(v, 16, 64);
        v += __shfl_xor(v, 32, 64);
        float inv = 1.0f / v;
        int ql = wave * 16 + l15;
        int tok = (wi * 8 + (ql >> 3)) * 48 + wj * 8 + (ql & 7);
        ushort_t* ob = O + (size_t)(b * Lh + tok) * Ch + h * 64;
        #pragma unroll
        for (int t4 = 0; t4 < 4; ++t4) {
            *(uint2*)&ob[t4 * 16 + quad * 4] =
                make_uint2(pack2bf(o_acc[t4][0] * inv, o_acc[t4][1] * inv),
                           pack2bf(o_acc[t4][2] * inv, o_acc[t4][3] * inv));
        }
    }
}

__global__ __launch_bounds__(256)
void attn_fused_kernel(const ushort_t* __restrict__ QKV, const float* __restrict__ fg,
                       float* __restrict__ Opart, float* __restrict__ Lpart,
                       ushort_t* __restrict__ ctxl)
{
    __shared__ ushort_t Ks[64][72];
    __shared__ ushort_t Vt[64][72];
    __shared__ ushort_t Ps[128][72];
    __shared__ float fgs[64];

    int bid = blockIdx.x;
    if (bid < 864) {
        // bijective XCD swizzle: 108 consecutive logical blocks per XCD.
        // Chunk = one half x 6 heads x 18 tiles -> 1.8 MB of K/V, L2-resident.
        int gid = (bid & 7) * 108 + (bid >> 3);
        int half = gid / 432;
        int rem = gid % 432;
        int tile = rem % 18;
        int h = (rem / 18) % NHh;
        int b = rem / 216;
        attn_global_body(QKV, fg, Opart, Lpart, tile, h, b, half, Ks, Vt, Ps, fgs);
    } else {
        int rr = bid - 864;
        int lid = (rr & 7) * 108 + (rr >> 3);
        int tile = lid % 36;
        int h = (lid / 36) % NHh;
        int b = lid / 432;
        attn_local_body(QKV, ctxl, tile, h, b, Ks, Vt, Ps);
    }
}

// ---------------------------------------------------------------- split-KV merge
// ctxg[r][d] = (Oa[r][d] + Ob[r][d]) / (La[r][h] + Lb[r][h]), bf16 out
__global__ __launch_bounds__(192)
void attn_merge_kernel(const float* __restrict__ Op, const float* __restrict__ Lp,
                       ushort_t* __restrict__ ctxg)
{
    int r = blockIdx.x;
    int tid = threadIdx.x;
    int d = tid * 4;
    int h = d >> 6;
    float la = Lp[(size_t)r * NHh + h];
    float lb = Lp[((size_t)4608 + r) * NHh + h];
    float inv = 1.0f / (la + lb);
    const float* pa = Op + (size_t)r * Ch + d;
    const float* pb = Op + (size_t)4608 * Ch + (size_t)r * Ch + d;
    float4 a = *(const float4*)pa;
    float4 b4 = *(const float4*)pb;
    *(uint2*)&ctxg[(size_t)r * Ch + d] =
        make_uint2(pack2bf((a.x + b4.x) * inv, (a.y + b4.y) * inv),
                   pack2bf((a.z + b4.z) * inv, (a.w + b4.w) * inv));
}

// ---------------------------------------------------------------- launch
extern "C" void kernel_launch(void* const* d_in, const int* in_sizes, int n_in,
                              void* d_out, int out_size, void* d_ws, size_t ws_size,
                              hipStream_t stream)
{
    const float* x       = (const float*)d_in[0];
    const float* mask    = (const float*)d_in[1];
    const float* w_qkv_g = (const float*)d_in[2];
    const float* b_qkv_g = (const float*)d_in[3];
    const float* w_o_g   = (const float*)d_in[4];
    const float* b_o_g   = (const float*)d_in[5];
    const float* w_qkv_l = (const float*)d_in[6];
    const float* b_qkv_l = (const float*)d_in[7];
    const float* w_o_l   = (const float*)d_in[8];
    const float* b_o_l   = (const float*)d_in[9];
    const float* ln1_w   = (const float*)d_in[10];
    const float* ln1_b   = (const float*)d_in[11];
    const float* ln2_w   = (const float*)d_in[12];
    const float* ln2_b   = (const float*)d_in[13];
    const float* w_fc1   = (const float*)d_in[14];
    const float* b_fc1   = (const float*)d_in[15];
    const float* w_fc2   = (const float*)d_in[16];
    const float* b_fc2   = (const float*)d_in[17];
    float* out = (float*)d_out;

    const size_t U = (size_t)Bh * Lh * Ch;           // 3,538,944
    char* p = (char*)d_ws;
    ushort_t* qkvb = (ushort_t*)p;        p += (size_t)4608 * 4608 * 2;  // [4608][4608] bf16
    ushort_t* midb = qkvb;                                               // [4608][3072] aliases
    ushort_t* ctxg = (ushort_t*)p;        p += U * 2;
    ushort_t* ctxl = (ushort_t*)p;        p += U * 2;
    ushort_t* xnb  = (ushort_t*)p;        p += U * 2;
    float*    Opart = (float*)p;          p += (size_t)2 * U * 4;        // f32 partials (2 halves)
    float*    Lpart = (float*)p;          p += (size_t)2 * 4608 * NHh * 4;
    float*    x1   = Opart;               // alias: x1 live only after merge consumed Opart
    ushort_t* wtq  = (ushort_t*)p;        p += (size_t)4608 * 768 * 2;   // qkv g|l concat
    ushort_t* wt_o_g = (ushort_t*)p;      p += (size_t)768 * 768 * 2;
    ushort_t* wt_o_l = (ushort_t*)p;      p += (size_t)768 * 768 * 2;
    ushort_t* wt_fc1 = (ushort_t*)p;      p += (size_t)3072 * 768 * 2;
    ushort_t* wt_fc2 = (ushort_t*)p;      p += (size_t)768 * 3072 * 2;
    float*    biasq  = (float*)p;         p += 4608 * 4;
    float*    fg     = (float*)p;         p += Bh * Lh * 4;
    float*    bgw    = (float*)p;

    const int Mrows = Bh * Lh;                   // 4608
    dim3 blk(256);

    hipMemcpyAsync(biasq, b_qkv_g, 2304 * sizeof(float), hipMemcpyDeviceToDevice, stream);
    hipMemcpyAsync(biasq + 2304, b_qkv_l, 2304 * sizeof(float), hipMemcpyDeviceToDevice, stream);

    transpose_all_kernel<<<2304, blk, 0, stream>>>(
        w_qkv_g, w_qkv_l, w_o_g, w_o_l, w_fc1, w_fc2,
        wtq, wt_o_g, wt_o_l, wt_fc1, wt_fc2);

    layernorm_bf16_kernel<<<Mrows, blk, 0, stream>>>(x, ln1_w, ln1_b, xnb);
    mask_kernel<<<72, dim3(64), 0, stream>>>(mask, fg, bgw);

    // fused QKV GEMM for both branches (N=4608)
    gemm_bf16_t<128><<<dim3(4608 / 128, Mrows / 128), blk, 0, stream>>>(
        xnb, wtq, biasq, nullptr, qkvb, Mrows, 4608, Ch, 2);

    // fused attention: 864 global split-KV blocks + 864 local blocks
    attn_fused_kernel<<<1728, blk, 0, stream>>>(qkvb, fg, Opart, Lpart, ctxl);
    attn_merge_kernel<<<Mrows, dim3(192), 0, stream>>>(Opart, Lpart, ctxg);

    // dual masked o-projection -> x1 (one dispatch)
    oproj_dual_kernel<<<dim3(Ch / 64, Mrows / 128), blk, 0, stream>>>(
        ctxg, ctxl, wt_o_g, wt_o_l, b_o_g, b_o_l, x, x1, fg, bgw);

    layernorm_bf16_kernel<<<Mrows, blk, 0, stream>>>(x1, ln2_w, ln2_b, xnb);

    // MLP
    gemm_bf16_t<128><<<dim3(3072 / 128, Mrows / 128), blk, 0, stream>>>(
        xnb, wt_fc1, b_fc1, nullptr, midb, Mrows, 3072, Ch, 1 | 2);
    gemm_bf16_t<64><<<dim3(Ch / 64, Mrows / 128), blk, 0, stream>>>(
        midb, wt_fc2, b_fc2, x1, out, Mrows, Ch, 3072, 0);
}

// Round 4
// 392.123 us; speedup vs baseline: 1.0948x; 1.0456x over previous
//
#include <hip/hip_runtime.h>
#include <math.h>

#define Lh 2304
#define Ch 768
#define NHh 12
#define Bh 2
#define QS2 3072  // row stride of packed qkv activation buffer [qg|kg|ql|kl]

typedef unsigned short ushort_t;
typedef unsigned int uint_t;
typedef __attribute__((ext_vector_type(8))) short bf16x8;
typedef __attribute__((ext_vector_type(4))) float f32x4;
#define MFMA16(a, b, c) __builtin_amdgcn_mfma_f32_16x16x32_bf16(a, b, c, 0, 0, 0)

// softmax in exp2 domain: exp(s*0.125 + m) == exp2(s*SCL2 + m*log2e)  (R1-validated)
#define SCL2 0.18033688f        // 0.125 * log2(e)
#define MSK2 1.4426950e9f       // 1e9  * log2(e)
#if __has_builtin(__builtin_amdgcn_exp2f)
#define EXP2F(x) __builtin_amdgcn_exp2f(x)
#else
#define EXP2F(x) exp2f(x)
#endif

__device__ __forceinline__ ushort_t f2bf(float f) {
    union { float f; uint_t u; } v; v.f = f;
    uint_t u = v.u + 0x7fffu + ((v.u >> 16) & 1u);   // RNE
    return (ushort_t)(u >> 16);
}
// pack 2 fp32 -> 2 bf16 (RNE) into one u32
__device__ __forceinline__ uint_t pack2bf(float a, float b) {
    return (uint_t)f2bf(a) | ((uint_t)f2bf(b) << 16);
}

// async global->LDS, 16B/lane, dest = wave-uniform base + lane*16
__device__ __forceinline__ void llds16(ushort_t* dst, const ushort_t* src) {
    __builtin_amdgcn_global_load_lds(
        (__attribute__((address_space(1))) void*)(const_cast<ushort_t*>(src)),
        (__attribute__((address_space(3))) void*)dst, 16, 0, 0);
}

// ---------------------------------------------------------------- layernorm (fp32 in, bf16 out)
__global__ __launch_bounds__(256)
void layernorm_bf16_kernel(const float* __restrict__ x, const float* __restrict__ w,
                           const float* __restrict__ b, ushort_t* __restrict__ y)
{
    int row = blockIdx.x;
    int tid = threadIdx.x;
    const float* xr = x + (size_t)row * Ch;
    float v0 = xr[tid], v1 = xr[tid + 256], v2 = xr[tid + 512];
    __shared__ float red[256];
    red[tid] = v0 + v1 + v2;
    __syncthreads();
    for (int st = 128; st > 0; st >>= 1) {
        if (tid < st) red[tid] += red[tid + st];
        __syncthreads();
    }
    float mean = red[0] * (1.0f / 768.0f);
    __syncthreads();
    float d0 = v0 - mean, d1 = v1 - mean, d2 = v2 - mean;
    red[tid] = d0 * d0 + d1 * d1 + d2 * d2;
    __syncthreads();
    for (int st = 128; st > 0; st >>= 1) {
        if (tid < st) red[tid] += red[tid + st];
        __syncthreads();
    }
    float rstd = rsqrtf(red[0] * (1.0f / 768.0f) + 1e-6f);
    ushort_t* yr = y + (size_t)row * Ch;
    yr[tid]       = f2bf(d0 * rstd * w[tid]       + b[tid]);
    yr[tid + 256] = f2bf(d1 * rstd * w[tid + 256] + b[tid + 256]);
    yr[tid + 512] = f2bf(d2 * rstd * w[tid + 512] + b[tid + 512]);
}

// ---------------------------------------------------------------- fused mask kernel
__global__ __launch_bounds__(64)
void mask_kernel(const float* __restrict__ mask, float* __restrict__ fg,
                 float* __restrict__ bgw)
{
    int win = blockIdx.x;            // 0..71
    int b = win / 36, w = win % 36;
    int wi = w / 6, wj = w % 6;
    int lane = threadIdx.x;          // 64
    int i = wi * 8 + (lane >> 3), j = wj * 8 + (lane & 7);
    const float* mb = mask + (size_t)b * 192 * 192 + (size_t)(i * 4) * 192 + j * 4;
    float s = 0.0f;
    #pragma unroll
    for (int di = 0; di < 4; ++di) {
        float4 v = *(const float4*)(mb + (size_t)di * 192);
        s += v.x + v.y + v.z + v.w;
    }
    float f = (s * (1.0f / 16.0f) > 0.4f) ? 1.0f : 0.0f;
    fg[b * Lh + i * 48 + j] = f;
    unsigned long long bg = __ballot(f == 0.0f);
    if (lane == 0) bgw[win] = bg ? 1.0f : 0.0f;
}

// ---------------------------------------------------------------- batched weight cast+transpose
__global__ __launch_bounds__(256)
void transpose_all_kernel(const float* __restrict__ w_qkv_g, const float* __restrict__ w_qkv_l,
                          const float* __restrict__ w_o_g, const float* __restrict__ w_o_l,
                          const float* __restrict__ w_fc1, const float* __restrict__ w_fc2,
                          ushort_t* __restrict__ wtq, ushort_t* __restrict__ wt_o_g,
                          ushort_t* __restrict__ wt_o_l, ushort_t* __restrict__ wt_fc1,
                          ushort_t* __restrict__ wt_fc2)
{
    int blk = blockIdx.x;
    const float* W; ushort_t* D; int K, N, nx, bx;
    const size_t CC = (size_t)Ch * Ch;
    if (blk < 432)       { int t = blk / 144; bx = blk % 144;
                           W = w_qkv_g + t * CC; D = wtq + t * CC; K = 768; N = 768; nx = 12; }
    else if (blk < 864)  { int r = blk - 432; int t = r / 144; bx = r % 144;
                           W = w_qkv_l + t * CC; D = wtq + (size_t)2304 * 768 + t * CC;
                           K = 768; N = 768; nx = 12; }
    else if (blk < 1008) { bx = blk - 864;  W = w_o_g; D = wt_o_g; K = 768; N = 768; nx = 12; }
    else if (blk < 1152) { bx = blk - 1008; W = w_o_l; D = wt_o_l; K = 768; N = 768; nx = 12; }
    else if (blk < 1728) { bx = blk - 1152; W = w_fc1; D = wt_fc1; K = 768; N = 3072; nx = 48; }
    else                 { bx = blk - 1728; W = w_fc2; D = wt_fc2; K = 3072; N = 768; nx = 12; }
    int n0 = (bx % nx) * 64;
    int k0 = (bx / nx) * 64;
    int tid = threadIdx.x;
    __shared__ float T[64][65];
    #pragma unroll
    for (int i = 0; i < 16; ++i) {
        int lin = i * 256 + tid;
        int r = lin >> 6, c = lin & 63;
        T[r][c] = W[(size_t)(k0 + r) * N + n0 + c];
    }
    __syncthreads();
    // vectorized: each unit = (n-row r, 4 consecutive k) -> one b64 store
    #pragma unroll
    for (int i = 0; i < 4; ++i) {
        int lin = i * 256 + tid;          // 0..1023
        int r = lin >> 4, c0 = (lin & 15) * 4;
        uint_t lo = pack2bf(T[c0][r], T[c0 + 1][r]);
        uint_t hi = pack2bf(T[c0 + 2][r], T[c0 + 3][r]);
        *(uint2*)&D[(size_t)(n0 + r) * K + k0 + c0] = make_uint2(lo, hi);
    }
}

// ---------------------------------------------------------------- bf16 MFMA GEMM (BM=128, BN template)
// flags: 1=gelu, 2=bf16 out, 4=qkv split-store (packed [qg|kg|ql|kl] -> C stride
// 3072; V column-blocks stored TRANSPOSED to vt[col'][row] for attn llds16)
template<int BNt>
__global__ __launch_bounds__(256)
void gemm_bf16_t(const ushort_t* __restrict__ A, const ushort_t* __restrict__ Bt,
                 const float* __restrict__ bias, const float* __restrict__ residual,
                 void* __restrict__ C, ushort_t* __restrict__ vt,
                 int M, int N, int K, int flags)
{
    __shared__ ushort_t AsL[2][128 * 32];
    __shared__ ushort_t BsL[2][BNt * 32];
    int bm = blockIdx.y * 128;
    int bn = blockIdx.x * BNt;
    int tid = threadIdx.x;
    int lane = tid & 63;
    int wave = tid >> 6;
    int wm = wave >> 1, wn = wave & 1;
    int quad = lane >> 4, l15 = lane & 15;
    constexpr int NJ = BNt / 32;

    int srow = lane >> 2;
    int sg8 = ((lane & 3) ^ ((lane >> 3) & 3)) * 8;
    int fsw = (l15 >> 1) & 3;

    f32x4 acc[4][NJ];
    #pragma unroll
    for (int i = 0; i < 4; ++i)
        #pragma unroll
        for (int j = 0; j < NJ; ++j)
            acc[i][j] = (f32x4){0.f, 0.f, 0.f, 0.f};

    int iters = K / 32;
    llds16(&AsL[0][wave * 512], A + (size_t)(bm + wave * 16 + srow) * K + sg8);
    llds16(&AsL[0][(wave + 4) * 512], A + (size_t)(bm + (wave + 4) * 16 + srow) * K + sg8);
    llds16(&BsL[0][wave * 512], Bt + (size_t)(bn + wave * 16 + srow) * K + sg8);
    if (BNt == 128)
        llds16(&BsL[0][(wave + 4) * 512], Bt + (size_t)(bn + (wave + 4) * 16 + srow) * K + sg8);

    for (int kt = 0; kt < iters; ++kt) {
        int cur = kt & 1;
        __syncthreads();

        bf16x8 af[4], bfr[NJ];
        #pragma unroll
        for (int i = 0; i < 4; ++i)
            af[i] = *(const bf16x8*)&AsL[cur][(wm * 64 + i * 16 + l15) * 32 + ((quad ^ fsw) * 8)];
        #pragma unroll
        for (int j = 0; j < NJ; ++j)
            bfr[j] = *(const bf16x8*)&BsL[cur][(wn * (BNt / 2) + j * 16 + l15) * 32 + ((quad ^ fsw) * 8)];

        if (kt + 1 < iters) {
            int k0 = (kt + 1) * 32;
            int nxt = 1 - cur;
            llds16(&AsL[nxt][wave * 512], A + (size_t)(bm + wave * 16 + srow) * K + k0 + sg8);
            llds16(&AsL[nxt][(wave + 4) * 512], A + (size_t)(bm + (wave + 4) * 16 + srow) * K + k0 + sg8);
            llds16(&BsL[nxt][wave * 512], Bt + (size_t)(bn + wave * 16 + srow) * K + k0 + sg8);
            if (BNt == 128)
                llds16(&BsL[nxt][(wave + 4) * 512], Bt + (size_t)(bn + (wave + 4) * 16 + srow) * K + k0 + sg8);
        }

        // swapped operands: lane = A row (output row), quad*4+r = B row (output col)
        #pragma unroll
        for (int i = 0; i < 4; ++i)
            #pragma unroll
            for (int j = 0; j < NJ; ++j)
                acc[i][j] = MFMA16(bfr[j], af[i], acc[i][j]);
    }

    #pragma unroll
    for (int i = 0; i < 4; ++i) {
        int row = bm + wm * 64 + i * 16 + l15;
        #pragma unroll
        for (int j = 0; j < NJ; ++j) {
            int col = bn + wn * (BNt / 2) + j * 16 + quad * 4;
            float4 bia = *(const float4*)&bias[col];
            float o0 = acc[i][j][0] + bia.x;
            float o1 = acc[i][j][1] + bia.y;
            float o2 = acc[i][j][2] + bia.z;
            float o3 = acc[i][j][3] + bia.w;
            if (flags & 1) {
                o0 = o0 * 0.5f * (1.0f + erff(o0 * 0.70710678f));
                o1 = o1 * 0.5f * (1.0f + erff(o1 * 0.70710678f));
                o2 = o2 * 0.5f * (1.0f + erff(o2 * 0.70710678f));
                o3 = o3 * 0.5f * (1.0f + erff(o3 * 0.70710678f));
            }
            if (residual) {
                float4 rs = *(const float4*)&residual[(size_t)row * N + col];
                o0 += rs.x; o1 += rs.y; o2 += rs.z; o3 += rs.w;
            }
            if (flags & 4) {
                // block-uniform branch (768-aligned regions, BNt=128 tiles)
                if ((col >= 1536 && col < 2304) || col >= 3840) {
                    int colp = col - ((col >= 3840) ? 3072 : 1536);
                    vt[(size_t)(colp)     * 4608 + row] = f2bf(o0);
                    vt[(size_t)(colp + 1) * 4608 + row] = f2bf(o1);
                    vt[(size_t)(colp + 2) * 4608 + row] = f2bf(o2);
                    vt[(size_t)(colp + 3) * 4608 + row] = f2bf(o3);
                } else {
                    int cq = col - ((col >= 2304) ? 768 : 0);
                    *(uint2*)&((ushort_t*)C)[(size_t)row * QS2 + cq] =
                        make_uint2(pack2bf(o0, o1), pack2bf(o2, o3));
                }
            } else if (flags & 2) {
                *(uint2*)&((ushort_t*)C)[(size_t)row * N + col] =
                    make_uint2(pack2bf(o0, o1), pack2bf(o2, o3));
            } else {
                *(float4*)&((float*)C)[(size_t)row * N + col] =
                    make_float4(o0, o1, o2, o3);
            }
        }
    }
}

// ---------------------------------------------------------------- dual o-projection
__global__ __launch_bounds__(256)
void oproj_dual_kernel(const ushort_t* __restrict__ ctxg, const ushort_t* __restrict__ ctxl,
                       const ushort_t* __restrict__ Wg, const ushort_t* __restrict__ Wl,
                       const float* __restrict__ biasg, const float* __restrict__ biasl,
                       const float* __restrict__ x, float* __restrict__ x1,
                       const float* __restrict__ fg, const float* __restrict__ bgw)
{
    __shared__ ushort_t AsL[2][128 * 32];
    __shared__ ushort_t BsL[2][64 * 32];
    int bm = blockIdx.y * 128;
    int bn = blockIdx.x * 64;
    int tid = threadIdx.x;
    int lane = tid & 63;
    int wave = tid >> 6;
    int wm = wave >> 1, wn = wave & 1;
    int quad = lane >> 4, l15 = lane & 15;

    int srow = lane >> 2;
    int sg8 = ((lane & 3) ^ ((lane >> 3) & 3)) * 8;
    int fsw = (l15 >> 1) & 3;
    const int K = Ch, N = Ch, iters = Ch / 32;

    f32x4 accg[4][2], accl[4][2];
    #pragma unroll
    for (int i = 0; i < 4; ++i)
        #pragma unroll
        for (int j = 0; j < 2; ++j) {
            accg[i][j] = (f32x4){0.f, 0.f, 0.f, 0.f};
            accl[i][j] = (f32x4){0.f, 0.f, 0.f, 0.f};
        }

    #pragma unroll
    for (int pass = 0; pass < 2; ++pass) {
        const ushort_t* A = pass ? ctxl : ctxg;
        const ushort_t* Bt = pass ? Wl : Wg;
        if (pass) __syncthreads();
        llds16(&AsL[0][wave * 512], A + (size_t)(bm + wave * 16 + srow) * K + sg8);
        llds16(&AsL[0][(wave + 4) * 512], A + (size_t)(bm + (wave + 4) * 16 + srow) * K + sg8);
        llds16(&BsL[0][wave * 512], Bt + (size_t)(bn + wave * 16 + srow) * K + sg8);

        for (int kt = 0; kt < iters; ++kt) {
            int cur = kt & 1;
            __syncthreads();
            bf16x8 af[4], bfr[2];
            #pragma unroll
            for (int i = 0; i < 4; ++i)
                af[i] = *(const bf16x8*)&AsL[cur][(wm * 64 + i * 16 + l15) * 32 + ((quad ^ fsw) * 8)];
            #pragma unroll
            for (int j = 0; j < 2; ++j)
                bfr[j] = *(const bf16x8*)&BsL[cur][(wn * 32 + j * 16 + l15) * 32 + ((quad ^ fsw) * 8)];
            if (kt + 1 < iters) {
                int k0 = (kt + 1) * 32;
                int nxt = 1 - cur;
                llds16(&AsL[nxt][wave * 512], A + (size_t)(bm + wave * 16 + srow) * K + k0 + sg8);
                llds16(&AsL[nxt][(wave + 4) * 512], A + (size_t)(bm + (wave + 4) * 16 + srow) * K + k0 + sg8);
                llds16(&BsL[nxt][wave * 512], Bt + (size_t)(bn + wave * 16 + srow) * K + k0 + sg8);
            }
            if (pass == 0) {
                #pragma unroll
                for (int i = 0; i < 4; ++i)
                    #pragma unroll
                    for (int j = 0; j < 2; ++j)
                        accg[i][j] = MFMA16(bfr[j], af[i], accg[i][j]);
            } else {
                #pragma unroll
                for (int i = 0; i < 4; ++i)
                    #pragma unroll
                    for (int j = 0; j < 2; ++j)
                        accl[i][j] = MFMA16(bfr[j], af[i], accl[i][j]);
            }
        }
    }

    #pragma unroll
    for (int i = 0; i < 4; ++i) {
        int row = bm + wm * 64 + i * 16 + l15;
        int bb = (row >= Lh) ? 1 : 0;
        int n = row - bb * Lh;
        int ii = n / 48, jj = n % 48;
        float keepg = (fg[row] != 0.0f) ? 1.0f : 0.0f;
        float keepl = (keepg == 0.0f &&
                       bgw[bb * 36 + (ii >> 3) * 6 + (jj >> 3)] != 0.0f) ? 1.0f : 0.0f;
        #pragma unroll
        for (int j = 0; j < 2; ++j) {
            int col = bn + wn * 32 + j * 16 + quad * 4;
            float4 bg4 = *(const float4*)&biasg[col];
            float4 bl4 = *(const float4*)&biasl[col];
            float4 x4 = *(const float4*)&x[(size_t)row * N + col];
            float4 o;
            o.x = x4.x + keepg * (accg[i][j][0] + bg4.x) + keepl * (accl[i][j][0] + bl4.x);
            o.y = x4.y + keepg * (accg[i][j][1] + bg4.y) + keepl * (accl[i][j][1] + bl4.y);
            o.z = x4.z + keepg * (accg[i][j][2] + bg4.z) + keepl * (accl[i][j][2] + bl4.z);
            o.w = x4.w + keepg * (accg[i][j][3] + bg4.w) + keepl * (accl[i][j][3] + bl4.w);
            *(float4*)&x1[(size_t)row * N + col] = o;
        }
    }
}

// ---------------------------------------------------------------- fused attention (global + local)
// R14: zero-register staging. K and V^T (produced transposed by the QKV GEMM)
// stream into LDS via global_load_lds (16B/lane), double-buffered, in the
// GEMM-proven [step][row][32] fsw-XOR layout. No scatter, no uint4 prefetch.
// Split-KV retained from R3 (half the keys per block, merge kernel).
__device__ __forceinline__ void attn_global_body(
    const ushort_t* __restrict__ QKV, const ushort_t* __restrict__ VT,
    const float* __restrict__ fg,
    float* __restrict__ Opart, float* __restrict__ Lpart,
    int tile, int h, int b, int half,
    ushort_t (*Ks)[2][64][32], ushort_t (*Vs)[2][64][32],
    ushort_t (*Ps)[72], float (*fgs)[64])
{
    int tid = threadIdx.x;
    int lane = tid & 63;
    int wave = tid >> 6;
    int quad = lane >> 4, l15 = lane & 15;
    int kb0 = half * 1152;            // key-token base for this half

    bf16x8 aq[2][2];
    #pragma unroll
    for (int s = 0; s < 2; ++s) {
        int tok = tile * 128 + wave * 32 + s * 16 + l15;
        const ushort_t* qbase = QKV + (size_t)(b * Lh + tok) * QS2 + h * 64;
        #pragma unroll
        for (int step = 0; step < 2; ++step)
            aq[s][step] = *(const bf16x8*)(qbase + step * 32 + quad * 8);
    }

    // staging source pointers (per-lane, tile 0): row = wave*16 + (lane>>2),
    // chunk (lane&3) holds logical chunk (lane&3)^fsw(row) -> read undoes XOR
    int srow = lane >> 2;
    int sc = lane & 3;
    int krow = wave * 16 + srow;
    int scx = (sc ^ ((krow >> 1) & 3)) * 8;
    const ushort_t* ksrc = QKV + (size_t)(b * Lh + kb0 + krow) * QS2 + 768 + h * 64 + scx;
    const ushort_t* vsrc = VT + (size_t)(h * 64 + krow) * 4608 + b * Lh + kb0 + scx;

    float l_part[2] = {0.f, 0.f};
    f32x4 o_acc[2][4];
    #pragma unroll
    for (int s = 0; s < 2; ++s)
        #pragma unroll
        for (int t4 = 0; t4 < 4; ++t4) o_acc[s][t4] = (f32x4){0.f, 0.f, 0.f, 0.f};

    // prologue: stage tile 0 into buf 0
    llds16(&Ks[0][0][wave * 16][0], ksrc);
    llds16(&Ks[0][1][wave * 16][0], ksrc + 32);
    llds16(&Vs[0][0][wave * 16][0], vsrc);
    llds16(&Vs[0][1][wave * 16][0], vsrc + 32);
    if (tid < 64) fgs[0][tid] = (fg[b * Lh + kb0 + tid] - 1.0f) * MSK2;

    int rfs = (l15 >> 1) & 3;

    for (int kt = 0; kt < 18; ++kt) {
        int cur = kt & 1, nxt = cur ^ 1;
        __syncthreads();

        bf16x8 bk[2][4];
        #pragma unroll
        for (int step = 0; step < 2; ++step)
            #pragma unroll
            for (int j4 = 0; j4 < 4; ++j4)
                bk[step][j4] = *(const bf16x8*)&Ks[cur][step][j4 * 16 + l15][(quad ^ rfs) * 8];

        if (kt + 1 < 18) {
            const ushort_t* kp = ksrc + (size_t)(kt + 1) * 64 * QS2;
            const ushort_t* vp = vsrc + (kt + 1) * 64;
            llds16(&Ks[nxt][0][wave * 16][0], kp);
            llds16(&Ks[nxt][1][wave * 16][0], kp + 32);
            llds16(&Vs[nxt][0][wave * 16][0], vp);
            llds16(&Vs[nxt][1][wave * 16][0], vp + 32);
            if (tid < 64) fgs[nxt][tid] = (fg[b * Lh + kb0 + (kt + 1) * 64 + tid] - 1.0f) * MSK2;
        }

        f32x4 s4[2][4];
        #pragma unroll
        for (int s = 0; s < 2; ++s)
            #pragma unroll
            for (int j4 = 0; j4 < 4; ++j4) s4[s][j4] = (f32x4){0.f, 0.f, 0.f, 0.f};
        #pragma unroll
        for (int step = 0; step < 2; ++step)
            #pragma unroll
            for (int s = 0; s < 2; ++s)
                #pragma unroll
                for (int j4 = 0; j4 < 4; ++j4)
                    s4[s][j4] = MFMA16(bk[step][j4], aq[s][step], s4[s][j4]);

        #pragma unroll
        for (int s = 0; s < 2; ++s) {
            int p0 = wave * 32 + s * 16;
            #pragma unroll
            for (int j4 = 0; j4 < 4; ++j4) {
                float4 mb4 = *(const float4*)&fgs[cur][j4 * 16 + quad * 4];
                float e0 = EXP2F(s4[s][j4][0] * SCL2 + mb4.x);
                float e1 = EXP2F(s4[s][j4][1] * SCL2 + mb4.y);
                float e2 = EXP2F(s4[s][j4][2] * SCL2 + mb4.z);
                float e3 = EXP2F(s4[s][j4][3] * SCL2 + mb4.w);
                l_part[s] += (e0 + e1) + (e2 + e3);
                uint_t a01 = __builtin_amdgcn_perm(__float_as_uint(e1), __float_as_uint(e0), 0x07060302u);
                uint_t a23 = __builtin_amdgcn_perm(__float_as_uint(e3), __float_as_uint(e2), 0x07060302u);
                *(uint2*)&Ps[p0 + l15][j4 * 16 + quad * 4] = make_uint2(a01, a23);
            }
        }
        #pragma unroll
        for (int step = 0; step < 2; ++step) {
            bf16x8 bv[4];
            #pragma unroll
            for (int t4 = 0; t4 < 4; ++t4)
                bv[t4] = *(const bf16x8*)&Vs[cur][step][t4 * 16 + l15][(quad ^ rfs) * 8];
            #pragma unroll
            for (int s = 0; s < 2; ++s) {
                int p0 = wave * 32 + s * 16;
                bf16x8 a = *(const bf16x8*)&Ps[p0 + l15][step * 32 + quad * 8];
                #pragma unroll
                for (int t4 = 0; t4 < 4; ++t4)
                    o_acc[s][t4] = MFMA16(bv[t4], a, o_acc[s][t4]);   // swapped: lane=q
            }
        }
    }

    // partial outputs: unnormalized o (f32) + l per (q,h)
    #pragma unroll
    for (int s = 0; s < 2; ++s) {
        float v = l_part[s];
        v += __shfl_xor(v, 16, 64);
        v += __shfl_xor(v, 32, 64);
        int ql = wave * 32 + s * 16 + l15;
        int tok = tile * 128 + ql;
        float* op = Opart + ((size_t)half * 4608 + b * Lh + tok) * Ch + h * 64;
        #pragma unroll
        for (int t4 = 0; t4 < 4; ++t4)
            *(f32x4*)&op[t4 * 16 + quad * 4] = o_acc[s][t4];
        if (quad == 0)
            Lpart[((size_t)half * 4608 + b * Lh + tok) * NHh + h] = v;
    }
}

__device__ __forceinline__ void attn_local_body(
    const ushort_t* __restrict__ QKV, const ushort_t* __restrict__ VT,
    ushort_t* __restrict__ O, int tile, int h, int b,
    ushort_t (*Ks)[2][64][32], ushort_t (*Vs)[2][64][32], ushort_t (*Ps)[72])
{
    int tid = threadIdx.x;
    int lane = tid & 63;
    int wave = tid >> 6;
    int quad = lane >> 4, l15 = lane & 15;
    int wi = tile / 6, wj = tile % 6;

    bf16x8 aq[2];
    {
        int ql = wave * 16 + l15;
        int tok = (wi * 8 + (ql >> 3)) * 48 + wj * 8 + (ql & 7);
        const ushort_t* qbase = QKV + (size_t)(b * Lh + tok) * QS2 + 1536 + h * 64;
        #pragma unroll
        for (int step = 0; step < 2; ++step)
            aq[step] = *(const bf16x8*)(qbase + step * 32 + quad * 8);
    }

    // staging: K rows = window tokens; V rows = d, chunks = token-groups
    {
        int srow = lane >> 2;
        int sc = lane & 3;
        int krow = wave * 16 + srow;
        int kfs = (krow >> 1) & 3;
        int tokK = (wi * 8 + (krow >> 3)) * 48 + wj * 8 + (krow & 7);
        const ushort_t* ksrc = QKV + (size_t)(b * Lh + tokK) * QS2 + 2304 + h * 64 + (sc ^ kfs) * 8;
        int c0 = sc ^ kfs;
        const ushort_t* vbase = VT + (size_t)(768 + h * 64 + krow) * 4608 + b * Lh + wj * 8;
        llds16(&Ks[0][0][wave * 16][0], ksrc);
        llds16(&Ks[0][1][wave * 16][0], ksrc + 32);
        llds16(&Vs[0][0][wave * 16][0], vbase + (wi * 8 + c0) * 48);
        llds16(&Vs[0][1][wave * 16][0], vbase + (wi * 8 + 4 + c0) * 48);
    }
    __syncthreads();

    float l_part = 0.f;
    f32x4 o_acc[4];
    #pragma unroll
    for (int t4 = 0; t4 < 4; ++t4) o_acc[t4] = (f32x4){0.f, 0.f, 0.f, 0.f};

    int rfs = (l15 >> 1) & 3;
    f32x4 s4[4];
    #pragma unroll
    for (int j4 = 0; j4 < 4; ++j4) s4[j4] = (f32x4){0.f, 0.f, 0.f, 0.f};
    #pragma unroll
    for (int step = 0; step < 2; ++step) {
        bf16x8 bk[4];
        #pragma unroll
        for (int j4 = 0; j4 < 4; ++j4)
            bk[j4] = *(const bf16x8*)&Ks[0][step][j4 * 16 + l15][(quad ^ rfs) * 8];
        #pragma unroll
        for (int j4 = 0; j4 < 4; ++j4)
            s4[j4] = MFMA16(bk[j4], aq[step], s4[j4]);
    }
    int p0 = wave * 16;
    #pragma unroll
    for (int j4 = 0; j4 < 4; ++j4) {
        float e0 = EXP2F(s4[j4][0] * SCL2);
        float e1 = EXP2F(s4[j4][1] * SCL2);
        float e2 = EXP2F(s4[j4][2] * SCL2);
        float e3 = EXP2F(s4[j4][3] * SCL2);
        l_part += (e0 + e1) + (e2 + e3);
        uint_t a01 = __builtin_amdgcn_perm(__float_as_uint(e1), __float_as_uint(e0), 0x07060302u);
        uint_t a23 = __builtin_amdgcn_perm(__float_as_uint(e3), __float_as_uint(e2), 0x07060302u);
        *(uint2*)&Ps[p0 + l15][j4 * 16 + quad * 4] = make_uint2(a01, a23);
    }
    #pragma unroll
    for (int step = 0; step < 2; ++step) {
        bf16x8 bv[4];
        #pragma unroll
        for (int t4 = 0; t4 < 4; ++t4)
            bv[t4] = *(const bf16x8*)&Vs[0][step][t4 * 16 + l15][(quad ^ rfs) * 8];
        bf16x8 a = *(const bf16x8*)&Ps[p0 + l15][step * 32 + quad * 8];
        #pragma unroll
        for (int t4 = 0; t4 < 4; ++t4)
            o_acc[t4] = MFMA16(bv[t4], a, o_acc[t4]);   // swapped: lane=q
    }

    {
        float v = l_part;
        v += __shfl_xor(v, 16, 64);
        v += __shfl_xor(v, 32, 64);
        float inv = 1.0f / v;
        int ql = wave * 16 + l15;
        int tok = (wi * 8 + (ql >> 3)) * 48 + wj * 8 + (ql & 7);
        ushort_t* ob = O + (size_t)(b * Lh + tok) * Ch + h * 64;
        #pragma unroll
        for (int t4 = 0; t4 < 4; ++t4) {
            *(uint2*)&ob[t4 * 16 + quad * 4] =
                make_uint2(pack2bf(o_acc[t4][0] * inv, o_acc[t4][1] * inv),
                           pack2bf(o_acc[t4][2] * inv, o_acc[t4][3] * inv));
        }
    }
}

__global__ __launch_bounds__(256)
void attn_fused_kernel(const ushort_t* __restrict__ QKV, const ushort_t* __restrict__ VT,
                       const float* __restrict__ fg,
                       float* __restrict__ Opart, float* __restrict__ Lpart,
                       ushort_t* __restrict__ ctxl)
{
    __shared__ __align__(16) ushort_t Ks[2][2][64][32];
    __shared__ __align__(16) ushort_t Vs[2][2][64][32];
    __shared__ __align__(16) ushort_t Ps[128][72];
    __shared__ float fgs[2][64];

    int bid = blockIdx.x;
    if (bid < 864) {
        // bijective XCD swizzle: 108 consecutive logical blocks per XCD
        int gid = (bid & 7) * 108 + (bid >> 3);
        int half = gid / 432;
        int rem = gid % 432;
        int tile = rem % 18;
        int h = (rem / 18) % NHh;
        int b = rem / 216;
        attn_global_body(QKV, VT, fg, Opart, Lpart, tile, h, b, half, Ks, Vs, Ps, fgs);
    } else {
        int rr = bid - 864;
        int lid = (rr & 7) * 108 + (rr >> 3);
        int tile = lid % 36;
        int h = (lid / 36) % NHh;
        int b = lid / 432;
        attn_local_body(QKV, VT, ctxl, tile, h, b, Ks, Vs, Ps);
    }
}

// ---------------------------------------------------------------- split-KV merge
// ctxg[r][d] = (Oa[r][d] + Ob[r][d]) / (La[r][h] + Lb[r][h]), bf16 out
__global__ __launch_bounds__(192)
void attn_merge_kernel(const float* __restrict__ Op, const float* __restrict__ Lp,
                       ushort_t* __restrict__ ctxg)
{
    int r = blockIdx.x;
    int tid = threadIdx.x;
    int d = tid * 4;
    int h = d >> 6;
    float la = Lp[(size_t)r * NHh + h];
    float lb = Lp[((size_t)4608 + r) * NHh + h];
    float inv = 1.0f / (la + lb);
    const float* pa = Op + (size_t)r * Ch + d;
    const float* pb = Op + (size_t)4608 * Ch + (size_t)r * Ch + d;
    float4 a = *(const float4*)pa;
    float4 b4 = *(const float4*)pb;
    *(uint2*)&ctxg[(size_t)r * Ch + d] =
        make_uint2(pack2bf((a.x + b4.x) * inv, (a.y + b4.y) * inv),
                   pack2bf((a.z + b4.z) * inv, (a.w + b4.w) * inv));
}

// ---------------------------------------------------------------- launch
extern "C" void kernel_launch(void* const* d_in, const int* in_sizes, int n_in,
                              void* d_out, int out_size, void* d_ws, size_t ws_size,
                              hipStream_t stream)
{
    const float* x       = (const float*)d_in[0];
    const float* mask    = (const float*)d_in[1];
    const float* w_qkv_g = (const float*)d_in[2];
    const float* b_qkv_g = (const float*)d_in[3];
    const float* w_o_g   = (const float*)d_in[4];
    const float* b_o_g   = (const float*)d_in[5];
    const float* w_qkv_l = (const float*)d_in[6];
    const float* b_qkv_l = (const float*)d_in[7];
    const float* w_o_l   = (const float*)d_in[8];
    const float* b_o_l   = (const float*)d_in[9];
    const float* ln1_w   = (const float*)d_in[10];
    const float* ln1_b   = (const float*)d_in[11];
    const float* ln2_w   = (const float*)d_in[12];
    const float* ln2_b   = (const float*)d_in[13];
    const float* w_fc1   = (const float*)d_in[14];
    const float* b_fc1   = (const float*)d_in[15];
    const float* w_fc2   = (const float*)d_in[16];
    const float* b_fc2   = (const float*)d_in[17];
    float* out = (float*)d_out;

    const size_t U = (size_t)Bh * Lh * Ch;           // 3,538,944
    char* p = (char*)d_ws;
    ushort_t* qkvb = (ushort_t*)p;        p += (size_t)4608 * 3072 * 2;  // [4608][qg|kg|ql|kl]
    ushort_t* vtb  = (ushort_t*)p;        p += (size_t)1536 * 4608 * 2;  // V^T [col'][token]
    ushort_t* midb = qkvb;                                               // [4608][3072] aliases
    ushort_t* ctxg = (ushort_t*)p;        p += U * 2;
    ushort_t* ctxl = (ushort_t*)p;        p += U * 2;
    ushort_t* xnb  = (ushort_t*)p;        p += U * 2;
    float*    Opart = (float*)p;          p += (size_t)2 * U * 4;        // f32 partials (2 halves)
    float*    Lpart = (float*)p;          p += (size_t)2 * 4608 * NHh * 4;
    float*    x1   = Opart;               // alias: x1 live only after merge consumed Opart
    ushort_t* wtq  = (ushort_t*)p;        p += (size_t)4608 * 768 * 2;   // qkv g|l concat
    ushort_t* wt_o_g = (ushort_t*)p;      p += (size_t)768 * 768 * 2;
    ushort_t* wt_o_l = (ushort_t*)p;      p += (size_t)768 * 768 * 2;
    ushort_t* wt_fc1 = (ushort_t*)p;      p += (size_t)3072 * 768 * 2;
    ushort_t* wt_fc2 = (ushort_t*)p;      p += (size_t)768 * 3072 * 2;
    float*    biasq  = (float*)p;         p += 4608 * 4;
    float*    fg     = (float*)p;         p += Bh * Lh * 4;
    float*    bgw    = (float*)p;

    const int Mrows = Bh * Lh;                   // 4608
    dim3 blk(256);

    hipMemcpyAsync(biasq, b_qkv_g, 2304 * sizeof(float), hipMemcpyDeviceToDevice, stream);
    hipMemcpyAsync(biasq + 2304, b_qkv_l, 2304 * sizeof(float), hipMemcpyDeviceToDevice, stream);

    transpose_all_kernel<<<2304, blk, 0, stream>>>(
        w_qkv_g, w_qkv_l, w_o_g, w_o_l, w_fc1, w_fc2,
        wtq, wt_o_g, wt_o_l, wt_fc1, wt_fc2);

    layernorm_bf16_kernel<<<Mrows, blk, 0, stream>>>(x, ln1_w, ln1_b, xnb);
    mask_kernel<<<72, dim3(64), 0, stream>>>(mask, fg, bgw);

    // fused QKV GEMM for both branches (N=4608 logical; packed store + V^T)
    gemm_bf16_t<128><<<dim3(4608 / 128, Mrows / 128), blk, 0, stream>>>(
        xnb, wtq, biasq, nullptr, qkvb, vtb, Mrows, 4608, Ch, 4);

    // fused attention: 864 global split-KV blocks + 864 local blocks
    attn_fused_kernel<<<1728, blk, 0, stream>>>(qkvb, vtb, fg, Opart, Lpart, ctxl);
    attn_merge_kernel<<<Mrows, dim3(192), 0, stream>>>(Opart, Lpart, ctxg);

    // dual masked o-projection -> x1 (one dispatch)
    oproj_dual_kernel<<<dim3(Ch / 64, Mrows / 128), blk, 0, stream>>>(
        ctxg, ctxl, wt_o_g, wt_o_l, b_o_g, b_o_l, x, x1, fg, bgw);

    layernorm_bf16_kernel<<<Mrows, blk, 0, stream>>>(x1, ln2_w, ln2_b, xnb);

    // MLP
    gemm_bf16_t<128><<<dim3(3072 / 128, Mrows / 128), blk, 0, stream>>>(
        xnb, wt_fc1, b_fc1, nullptr, midb, nullptr, Mrows, 3072, Ch, 1 | 2);
    gemm_bf16_t<64><<<dim3(Ch / 64, Mrows / 128), blk, 0, stream>>>(
        midb, wt_fc2, b_fc2, x1, out, nullptr, Mrows, Ch, 3072, 0);
}